// Round 9
// baseline (721.945 us; speedup 1.0000x reference)
//
#include <hip/hip_runtime.h>
#include <math.h>
#include <stdint.h>
#include <stddef.h>

// TreeEnergyLoss on gfx950 — R18: R15 base + pair-prefetch k_dp.
//
//  * Chain model (fits R10/R14/R15/R16/R17): per-level cost = chained
//    load-latencies inside the clobber-protected region. R15 = 2 RTs/level
//    (pairS[i] then Al[pp]). Fix: prefetch next level's pair into REGISTERS
//    before the clobber (pairS is read-only, distinct __shared__ object;
//    registers survive the memory clobber) -> 1 RT/level.
//  * Arithmetic/order identical to R15 (absmax 0.0): same exprs, same
//    atomic scatter. Wide levels (>64) fall back to in-level pair loads.
//  * k_topo/k_mst/k_edgew/k_init/k_loss/k_final: exact R15 versions.

namespace {
constexpr int Bn  = 4, Cc = 21, Hh = 96, Ww = 96;
constexpr int Nn  = Hh * Ww;              // 9216
constexpr int EhE = Hh * (Ww - 1);        // 9120
constexpr int Ne  = EhE + (Hh - 1) * Ww;  // 18240
constexpr int Clow = 3, Chigh = 512;
constexpr int NCh = Cc + 1;               // 22
constexpr int MAXD = 2048;
constexpr int TL  = 2 * (Nn - 1);         // 18430 arcs
constexpr int ESL = 18432;
constexpr int SEG = 19;                   // ruler stride (odd)
constexpr int NR  = (TL + SEG - 1) / SEG; // 970 rulers
constexpr int MAXC = 4608;

// workspace layout (bytes) — 16B-aligned
constexpr size_t OFF_ACC  = 0;                                        // 2 doubles
constexpr size_t OFF_PROB = 256;                                      // float[B][21][Nn]
constexpr size_t OFF_S1   = OFF_PROB + (size_t)Bn * Cc * Nn * 4;      // float[B][22][Nn]
constexpr size_t OFF_S2   = OFF_S1   + (size_t)Bn * NCh * Nn * 4;     // float[B][22][Nn]
constexpr size_t OFF_EW   = OFF_S2   + (size_t)Bn * NCh * Nn * 4;     // double[8][Ne]
constexpr size_t OFF_ORD  = OFF_EW   + (size_t)8 * Ne * 8;            // int[8][Nn]
constexpr size_t OFF_PPOS = OFF_ORD  + (size_t)8 * Nn * 4;            // (legacy, unused)
constexpr size_t OFF_WGT  = OFF_PPOS + (size_t)8 * Nn * 2;            // (k_mst EL2 overlay)
constexpr size_t OFF_LEV  = OFF_WGT  + (size_t)8 * Nn * 4;            // int[8][MAXD]
constexpr size_t OFF_D    = OFF_LEV  + (size_t)8 * MAXD * 4;          // int[8]
constexpr size_t OFF_DIR  = OFF_D    + 256;                           // int[8][Nn]
constexpr size_t OFF_CBW  = OFF_DIR  + (size_t)8 * Nn * 4;            // 73728 B/tb: elemSeg | ORG+OWNR
constexpr size_t OFF_CBE  = OFF_CBW  + (size_t)8 * Nn * 8;            // ushort[8][ESL] ownG
constexpr size_t OFF_OPP  = OFF_CBE  + (size_t)8 * Nn * 4;            // ushort[8][ESL] oppG
constexpr size_t OFF_SGN  = OFF_OPP  + (size_t)8 * ESL * 2;           // ushort[8][Nn] IRG
constexpr size_t OFF_PNF  = OFF_SGN  + (size_t)8 * ESL;               // uint[8][Nn] (unused)
constexpr size_t OFF_RNK  = OFF_PNF  + (size_t)8 * Nn * 4;            // ushort[8][ESL] rank0
constexpr size_t OFF_PAIR = OFF_RNK  + (size_t)8 * ESL * 2;           // uint2[8][Nn] {w_bits, ppos}
// k_mst edge-list ping/pong overlaid on regions dead until k_topo:
constexpr size_t OFF_EL1  = OFF_ORD;                                  // ushort[8][Ne]
constexpr size_t OFF_EL2  = OFF_WGT;                                  // ushort[8][Ne]
} // namespace

__device__ __forceinline__ void edge_nodes(int e, int& a, int& b) {
    if (e < EhE) { int h = e / (Ww - 1), w = e - h * (Ww - 1); a = h * Ww + w; b = a + 1; }
    else { int e2 = e - EhE; int h = e2 / Ww, w = e2 - h * Ww; a = h * Ww + w; b = a + Ww; }
}
// dirs: 0=E(+1) 1=W(-1) 2=S(+96) 3=N(-96); rev(d)=d^1
__device__ __forceinline__ int dir_delta(int d) {
    return (d == 0) ? 1 : (d == 1) ? -1 : (d == 2) ? Ww : -Ww;
}
__device__ __forceinline__ int edge_of(int u, int d) {
    int h = u / Ww, w = u - h * Ww;
    if (d == 0) return h * (Ww - 1) + w;
    if (d == 1) return h * (Ww - 1) + w - 1;
    if (d == 2) return EhE + u;
    return EhE + u - Ww;
}

// 64-bit total-order key: (fixed-point weight, edge index)
__device__ __forceinline__ unsigned long long mkkey(double w, int e) {
    unsigned long long q = (unsigned long long)(w * 70368744177664.0);  // 2^46
    if (q >= (1ull << 49)) q = (1ull << 49) - 1;
    return (q << 15) | (unsigned)e;
}

// wave-aggregated compaction push
__device__ __forceinline__ void compact_push(bool keep, int val, int* cnt,
                                             unsigned short* out, int lane) {
    unsigned long long m = __ballot(keep ? 1 : 0);
    if (m == 0ull) return;
    int leader = __ffsll((unsigned long long)m) - 1;
    int base = 0;
    if (lane == leader) base = atomicAdd(cnt, __popcll(m));
    base = __shfl(base, leader, 64);
    if (keep) {
        unsigned long long lower = m & ((1ull << lane) - 1ull);
        out[base + __popcll(lower)] = (unsigned short)val;
    }
}

// inclusive block scan (1024 threads = 16 waves) via shfl; wsum = int[16] LDS
__device__ __forceinline__ int scan1024s(int val, int tid, int* wsum) {
    __syncthreads();                      // protect wsum reuse
    int lane = tid & 63, wv = tid >> 6;
    int x = val;
    #pragma unroll
    for (int off = 1; off < 64; off <<= 1) {
        int y = __shfl_up(x, off, 64);
        if (lane >= off) x += y;
    }
    if (lane == 63) wsum[wv] = x;
    __syncthreads();
    if (wv == 0) {
        int s2 = (lane < 16) ? wsum[lane] : 0;
        #pragma unroll
        for (int off = 1; off < 16; off <<= 1) {
            int y = __shfl_up(s2, off, 64);
            if (lane >= off) s2 += y;
        }
        if (lane < 16) wsum[lane] = s2;
    }
    __syncthreads();
    int base = (wv > 0) ? wsum[wv - 1] : 0;
    return x + base;
}

// legacy scan for k_mst (uses its own bufs)
__device__ __forceinline__ int scan1024_incl(int val, int tid, int* b0, int* b1) {
    b0[tid] = val;
    __syncthreads();
    int* s = b0; int* d = b1;
    for (int off = 1; off < 1024; off <<= 1) {
        int x = s[tid];
        if (tid >= off) x += s[tid - off];
        d[tid] = x;
        __syncthreads();
        int* t = s; s = d; d = t;
    }
    return s[tid];
}

__global__ void k_init(const float* __restrict__ preds, float* __restrict__ prob,
                       double* __restrict__ acc) {
    int idx = blockIdx.x * blockDim.x + threadIdx.x;
    if (idx == 0) { acc[0] = 0.0; acc[1] = 0.0; }
    if (idx >= Bn * Cc * Nn) return;
    prob[idx] = 1.0f / (1.0f + expf(-preds[idx]));
}

// exact float64 edge weights, sequential channel order (bit-identical).
__global__ void k_edgew(const float* __restrict__ feat, int C, double* __restrict__ ew) {
    int idx = blockIdx.x * blockDim.x + threadIdx.x;
    if (idx >= Bn * Ne) return;
    int b = idx / Ne, e = idx - b * Ne;
    int a, c2; edge_nodes(e, a, c2);
    const float* fa = feat + (size_t)b * C * Nn + a;
    const float* fb = feat + (size_t)b * C * Nn + c2;
    double s = 0.0;
    int c = 0;
    for (; c + 16 <= C; c += 16) {
        float va[16], vb[16];
        #pragma unroll
        for (int k = 0; k < 16; k++) {
            va[k] = fa[(size_t)(c + k) * Nn];
            vb[k] = fb[(size_t)(c + k) * Nn];
        }
        #pragma unroll
        for (int k = 0; k < 16; k++) {
            double d = (double)va[k] - (double)vb[k];
            s += d * d;
        }
    }
    for (; c < C; c++) {
        double d = (double)fa[(size_t)c * Nn] - (double)fb[(size_t)c * Nn];
        s += d * d;
    }
    ew[idx] = s;
}

// Boruvka MST, LDS-resident (R8 version). One block per (tree,batch) tb.
__global__ void __launch_bounds__(1024)
k_mst(char* __restrict__ ws) {
    const int tb = blockIdx.x, tid = threadIdx.x;
    const int lane = tid & 63;
    const double* ew = (const double*)(ws + OFF_EW) + (size_t)tb * Ne;
    int* dirG = (int*)(ws + OFF_DIR) + (size_t)tb * Nn;
    unsigned short* elA = (unsigned short*)(ws + OFF_EL1) + (size_t)tb * Ne;
    unsigned short* elB = (unsigned short*)(ws + OFF_EL2) + (size_t)tb * Ne;

    __shared__ unsigned short comp[Nn];
    __shared__ unsigned long long cbK[MAXC];
    __shared__ int scanBuf[2048];
    __shared__ int chgArr[48];
    __shared__ int sLen, sNC;

    unsigned short* nxtN     = (unsigned short*)cbK;
    unsigned short* newSlotN = (unsigned short*)cbK + Nn;
    unsigned short* nxt      = (unsigned short*)cbK;
    unsigned short* newSlot  = (unsigned short*)cbK + MAXC;

    for (int i = tid; i < Nn; i += 1024) dirG[i] = 0;
    if (tid < 48) chgArr[tid] = 0;
    __syncthreads();

    for (int i = tid; i < Nn; i += 1024) {
        int h = i / Ww, w = i - h * Ww;
        unsigned long long bk = ~0ull;
        if (w < Ww - 1) { int e = h * (Ww - 1) + w;     unsigned long long k = mkkey(ew[e], e); if (k < bk) bk = k; }
        if (w > 0)      { int e = h * (Ww - 1) + w - 1; unsigned long long k = mkkey(ew[e], e); if (k < bk) bk = k; }
        if (h < Hh - 1) { int e = EhE + i;              unsigned long long k = mkkey(ew[e], e); if (k < bk) bk = k; }
        if (h > 0)      { int e = EhE + i - Ww;         unsigned long long k = mkkey(ew[e], e); if (k < bk) bk = k; }
        int e = (int)(bk & 0x7FFF);
        int a, c; edge_nodes(e, a, c);
        nxtN[i] = (unsigned short)((a == i) ? c : a);
        int da = (c == a + 1) ? 0 : 2;
        atomicOr(&dirG[a], 1 << da);
        atomicOr(&dirG[c], 1 << (da ^ 1));
    }
    __syncthreads();
    for (int i = tid; i < Nn; i += 1024) {
        int o = nxtN[i];
        if (o != i && nxtN[o] == i && i < o) nxtN[i] = (unsigned short)i;
    }
    __syncthreads();
    {
        int it = 0;
        while (it < 40) {
            bool any = false;
            for (int r = tid; r < Nn; r += 1024) {
                int nr = nxtN[r], nnr = nxtN[nr];
                if (nr != nnr) { nxtN[r] = (unsigned short)nnr; any = true; }
            }
            if (any) chgArr[it] = 1;
            __syncthreads();
            if (!chgArr[it]) break;
            it++;
        }
    }
    {
        int base = tid * 9, cnt = 0, loc[9];
        #pragma unroll
        for (int k = 0; k < 9; k++) {
            int i = base + k;
            loc[k] = cnt;
            if (nxtN[i] == i) cnt++;
        }
        int incl = scan1024_incl(cnt, tid, scanBuf, scanBuf + 1024);
        int eb = incl - cnt;
        #pragma unroll
        for (int k = 0; k < 9; k++) {
            int i = base + k;
            if (nxtN[i] == i) newSlotN[i] = (unsigned short)(eb + loc[k]);
        }
        if (tid == 1023) sNC = incl;
    }
    __syncthreads();
    for (int i = tid; i < Nn; i += 1024) comp[i] = newSlotN[nxtN[i]];
    __syncthreads();
    int nComp = sNC;

    unsigned short* src = elA;
    unsigned short* dst = elB;
    int srcLen = -1;
    for (int round = 2; round < 22 && nComp > 1; round++) {
        if (tid == 0) sLen = 0;
        if (tid < 48) chgArr[tid] = 0;
        __syncthreads();
        if (srcLen < 0) {
            for (int e = tid; e < Ne; e += 1024) {
                int a, c; edge_nodes(e, a, c);
                compact_push(comp[a] != comp[c], e, &sLen, dst, lane);
            }
        } else {
            for (int k = tid; k < srcLen; k += 1024) {
                int e = src[k];
                int a, c; edge_nodes(e, a, c);
                compact_push(comp[a] != comp[c], e, &sLen, dst, lane);
            }
        }
        for (int s = tid; s < nComp; s += 1024) cbK[s] = ~0ull;
        __syncthreads();
        int len = sLen;
        if (len == 0) break;
        for (int k = tid; k < len; k += 1024) {
            int e = dst[k];
            int a, c; edge_nodes(e, a, c);
            unsigned long long key = mkkey(ew[e], e);
            atomicMin(&cbK[comp[a]], key);
            atomicMin(&cbK[comp[c]], key);
        }
        __syncthreads();
        unsigned long long kr[5];
        int nOwn = 0;
        for (int s = tid; s < nComp; s += 1024) kr[nOwn++] = cbK[s];
        __syncthreads();
        {
            int o = 0;
            for (int s = tid; s < nComp; s += 1024, o++) {
                unsigned long long key = kr[o];
                if (key != ~0ull) {
                    int e = (int)(key & 0x7FFF);
                    int a, c; edge_nodes(e, a, c);
                    int sa = comp[a], sc = comp[c];
                    nxt[s] = (unsigned short)((sa == s) ? sc : sa);
                    int da = (c == a + 1) ? 0 : 2;
                    atomicOr(&dirG[a], 1 << da);
                    atomicOr(&dirG[c], 1 << (da ^ 1));
                } else nxt[s] = (unsigned short)s;
            }
        }
        __syncthreads();
        for (int s = tid; s < nComp; s += 1024) {
            int o = nxt[s];
            if (o != s && nxt[o] == s && s < o) nxt[s] = (unsigned short)s;
        }
        __syncthreads();
        {
            int it = 0;
            while (it < 40) {
                bool any = false;
                for (int s = tid; s < nComp; s += 1024) {
                    int ns = nxt[s], nns = nxt[ns];
                    if (ns != nns) { nxt[s] = (unsigned short)nns; any = true; }
                }
                if (any) chgArr[it] = 1;
                __syncthreads();
                if (!chgArr[it]) break;
                it++;
            }
        }
        {
            int K = (nComp + 1023) >> 10;
            int base = tid * K, cnt = 0, loc[5];
            for (int k = 0; k < K; k++) {
                int s = base + k;
                loc[k] = cnt;
                if (s < nComp && nxt[s] == s) cnt++;
            }
            int incl = scan1024_incl(cnt, tid, scanBuf, scanBuf + 1024);
            int eb = incl - cnt;
            for (int k = 0; k < K; k++) {
                int s = base + k;
                if (s < nComp && nxt[s] == s) newSlot[s] = (unsigned short)(eb + loc[k]);
            }
            if (tid == 1023) sNC = incl;
        }
        __syncthreads();
        for (int i = tid; i < Nn; i += 1024) comp[i] = newSlot[nxt[comp[i]]];
        __syncthreads();
        nComp = sNC;
        unsigned short* t = src; src = dst; dst = t;
        srcLen = len;
    }
}

// Euler-tour topology — R12 core: batched gathers + binary-lifting center walk.
// Final phase emits packed pairG {w_bits, ppos} (+ levG as before). (R15 form)
__global__ void __launch_bounds__(1024)
k_topo(char* __restrict__ ws) {
    const int tb = blockIdx.x, tid = threadIdx.x;
    const int lane = tid & 63, wv = tid >> 6;
    const int tree = tb >> 2;
    const double* ew  = (const double*)(ws + OFF_EW) + (size_t)tb * Ne;
    const int*  dirG  = (const int*)(ws + OFF_DIR) + (size_t)tb * Nn;
    unsigned int*   elemSegG = (unsigned int*)(ws + OFF_CBW + (size_t)tb * 73728);
    unsigned short* ORG      = (unsigned short*)(ws + OFF_CBW + (size_t)tb * 73728);      // after P4
    unsigned short* OWNR     = ORG + ESL;
    unsigned short* ownG     = (unsigned short*)(ws + OFF_CBE + (size_t)tb * (size_t)ESL * 2);
    unsigned short* oppG     = (unsigned short*)(ws + OFF_OPP + (size_t)tb * (size_t)ESL * 2);
    unsigned short* IRG      = (unsigned short*)(ws + OFF_SGN + (size_t)tb * ESL);
    unsigned short* rank0G   = (unsigned short*)(ws + OFF_RNK + (size_t)tb * (size_t)ESL * 2);
    int*            ordG  = (int*)(ws + OFF_ORD)  + (size_t)tb * Nn;
    uint2*          pairG = (uint2*)(ws + OFF_PAIR) + (size_t)tb * Nn;
    int*            levG  = (int*)(ws + OFF_LEV)  + (size_t)tb * MAXD;
    int*            dG    = (int*)(ws + OFF_D);
    const float inv_sigma = tree ? 1.0f : 50.0f;

    __shared__ char A[36864];   // nxtS | rulers(P3) | scanS | J-tables | final tables
    __shared__ char B[18432];   // degOff -> depthS
    __shared__ char C[9216];    // nbS -> parC
    __shared__ int  wsum[16];
    __shared__ int  sR, sPack, sCenter;

    // ---- P0: masks -> LDS; degree prefix sums ----
    unsigned short* degOff = (unsigned short*)B;
    unsigned char*  nbS    = (unsigned char*)C;
    for (int i = tid; i < Nn; i += 1024) nbS[i] = (unsigned char)dirG[i];
    __syncthreads();
    {
        int base9 = tid * 9;
        int loc[9]; int s = 0;
        #pragma unroll
        for (int k = 0; k < 9; k++) { loc[k] = s; s += __popc(nbS[base9 + k]); }
        int incl = scan1024s(s, tid, wsum);
        int eb = incl - s;
        #pragma unroll
        for (int k = 0; k < 9; k++) degOff[base9 + k] = (unsigned short)(eb + loc[k]);
    }
    __syncthreads();

    // ---- P1: Euler successor + owner + opposite ----
    unsigned short* nxtS = (unsigned short*)A;
    for (int u = tid; u < Nn; u += 1024) {
        int m = nbS[u]; int base = degOff[u]; int k = 0;
        #pragma unroll
        for (int d = 0; d < 4; d++) {
            if (m & (1 << d)) {
                int v = u + dir_delta(d);
                int mv = nbS[v]; int rd = d ^ 1;
                int pv = __popc(mv & ((1 << rd) - 1));
                int dv = __popc(mv);
                int nx = pv + 1; if (nx == dv) nx = 0;
                int j = base + k;
                nxtS[j] = (unsigned short)(degOff[v] + nx);
                ownG[j] = (unsigned short)((u << 2) | d);
                oppG[j] = (unsigned short)(degOff[v] + pv);
                k++;
            }
        }
    }
    __syncthreads();

    // ---- P2: ruling-set walks ----
    int myNr = 0, myLen = 0;
    if (tid < NR) {
        int x = tid * SEG, off = 0;
        for (int g = 0; g < 4096; g++) {
            elemSegG[x] = ((unsigned)tid << 11) | (unsigned)off;
            int y = nxtS[x];
            if (y % SEG == 0) { myNr = y / SEG; myLen = off + 1; break; }
            x = y; off++;
        }
    }
    __syncthreads();

    // ---- P3: ruler pointer doubling (rulers live in C; nbS dead) ----
    unsigned short* cn  = (unsigned short*)C;
    unsigned short* cd  = (unsigned short*)(C + 2048);
    unsigned short* nn2 = (unsigned short*)(C + 4096);
    unsigned short* nd2 = (unsigned short*)(C + 6144);
    if (tid == 0)      { cn[0] = 0; cd[0] = 0; }
    else if (tid < NR) { cn[tid] = (unsigned short)myNr; cd[tid] = (unsigned short)myLen; }
    else               { cn[tid] = (unsigned short)tid; cd[tid] = 0; }
    __syncthreads();
    for (int r = 0; r < 10; r++) {
        int c = cn[tid];
        int dv = cd[tid] + cd[c];
        int n2 = cn[c];
        nn2[tid] = (unsigned short)n2; nd2[tid] = (unsigned short)dv;
        __syncthreads();
        unsigned short* t;
        t = cn; cn = nn2; nn2 = t;
        t = cd; cd = nd2; nd2 = t;
    }
    unsigned short* rb = nn2;
    rb[tid] = (tid == 0) ? 0 : (unsigned short)(TL - cd[tid]);
    __syncthreads();

    // ---- P4: per-element rank0 (batched loads) ----
    for (int hh = 0; hh < 2; hh++) {
        unsigned int pk4[9];
        #pragma unroll
        for (int t = 0; t < 9; t++) {
            int e = tid + (hh * 9 + t) * 1024;
            pk4[t] = elemSegG[e < TL ? e : 0];
        }
        unsigned short rbv[9];
        #pragma unroll
        for (int t = 0; t < 9; t++) rbv[t] = rb[pk4[t] >> 11];
        #pragma unroll
        for (int t = 0; t < 9; t++) {
            int e = tid + (hh * 9 + t) * 1024;
            if (e < TL) rank0G[e] = (unsigned short)(rbv[t] + (pk4[t] & 2047));
        }
    }
    __syncthreads();

    // ---- P5: rank-space reindex (elemSegG dead -> ORG/OWNR), batched ----
    for (int hh = 0; hh < 2; hh++) {
        unsigned short rnk[9], opp[9], own2[9];
        #pragma unroll
        for (int t = 0; t < 9; t++) {
            int j = tid + (hh * 9 + t) * 1024;
            int ja = j < TL ? j : 0;
            rnk[t] = rank0G[ja]; opp[t] = oppG[ja]; own2[t] = ownG[ja];
        }
        unsigned short r2[9];
        #pragma unroll
        for (int t = 0; t < 9; t++) r2[t] = rank0G[opp[t]];
        #pragma unroll
        for (int t = 0; t < 9; t++) {
            int j = tid + (hh * 9 + t) * 1024;
            if (j < TL) { int r = rnk[t]; ORG[r] = r2[t]; OWNR[r] = own2[t]; }
        }
    }
    {
        unsigned short dof[9];
        #pragma unroll
        for (int t = 0; t < 9; t++) dof[t] = degOff[tid + t * 1024];
        unsigned short ov[9];
        #pragma unroll
        for (int t = 0; t < 9; t++) ov[t] = oppG[dof[t]];
        unsigned short rv[9];
        #pragma unroll
        for (int t = 0; t < 9; t++) rv[t] = rank0G[ov[t]];
        #pragma unroll
        for (int t = 0; t < 9; t++) IRG[tid + t * 1024] = rv[t];
    }
    __syncthreads();

    // ---- 3 rounds: root 0 -> u -> (v, diam, lifted walk->center) -> center emit ----
    short* scanS = (short*)A;                 // overlays nxtS (dead)
    unsigned char* parC = (unsigned char*)C;  // overlays rulers (dead)
    unsigned short* depthB = (unsigned short*)B;  // overlays degOff (dead after P5)
    int curRoot = 0, rootC = 0;
    for (int ph = 0; ph < 3; ph++) {
        if (tid == 0) {
            sR = ORG[IRG[curRoot]];   // rank0 of root's first out-arc
            sPack = 0;
        }
        __syncthreads();
        const int R = sR;
        const bool doPar = (ph >= 1);
        // fused sign+scan pass over rotated rank positions (batched loads)
        int base = tid * 18;
        int n = TL - base; if (n > 18) n = 18; if (n < 0) n = 0;
        unsigned short orvA[18], ownA[18];
        #pragma unroll
        for (int k = 0; k < 18; k++) {
            int q = base + k;
            int r = q + R; if (r >= TL) r -= TL; if (q >= TL) r = 0;
            orvA[k] = ORG[r];
        }
        if (doPar) {
            #pragma unroll
            for (int k = 0; k < 18; k++) {
                int q = base + k;
                int r = q + R; if (r >= TL) r -= TL; if (q >= TL) r = 0;
                ownA[k] = OWNR[r];
            }
        }
        short loc[18]; int s = 0;
        #pragma unroll
        for (int k = 0; k < 18; k++) {
            if (k < n) {
                int q = base + k;
                int rro = (int)orvA[k] - R; if (rro < 0) rro += TL;
                bool desc = q < rro;
                if (doPar && desc) {
                    int own = ownA[k];
                    int head = (own >> 2) + dir_delta(own & 3);
                    parC[head] = (unsigned char)((own & 3) ^ 1);
                }
                s += desc ? 1 : -1;
                loc[k] = (short)s;
            }
        }
        int incl = scan1024s(s, tid, wsum);
        int eb = incl - s;
        #pragma unroll
        for (int k = 0; k < 18; k++)
            if (k < n) scanS[base + k] = (short)(loc[k] + eb);
        __syncthreads();
        // depth gather (batched) + wave-reduced argmax
        int pk = 0;
        {
            unsigned short qA[9];
            #pragma unroll
            for (int j = 0; j < 9; j++) qA[j] = IRG[tid + j * 1024];
            int depA[9];
            #pragma unroll
            for (int j = 0; j < 9; j++) {
                int q = (int)qA[j] - R; if (q < 0) q += TL;
                depA[j] = (int)scanS[q];
            }
            #pragma unroll
            for (int j = 0; j < 9; j++) {
                int x = tid + j * 1024;
                int dep = (x == curRoot) ? 0 : depA[j];
                int p2 = (dep << 14) | x;
                if (p2 > pk) pk = p2;
                if (ph == 2) depthB[x] = (unsigned short)dep;
            }
        }
        #pragma unroll
        for (int off = 32; off > 0; off >>= 1) {
            int o = __shfl_down(pk, off, 64);
            if (o > pk) pk = o;
        }
        if (lane == 0) atomicMax(&sPack, pk);
        __syncthreads();
        if (ph == 0) curRoot = sPack & 16383;
        else if (ph == 1) {
            // binary-lifting walk: jump ceil(diam/2) parent-hops from v.
            // J tables overlay A (scanS dead until round 2 rebuilds it).
            int diam = sPack >> 14, v = sPack & 16383;
            int steps = diam - (diam >> 1);
            unsigned short* J  = (unsigned short*)A;
            unsigned short* J2 = (unsigned short*)(A + 18432);
            for (int x = tid; x < Nn; x += 1024)
                J[x] = (unsigned short)((x == curRoot) ? x : (x + dir_delta(parC[x])));
            if (tid == 0) sCenter = v;
            __syncthreads();
            for (int k = 0; (steps >> k) != 0; k++) {
                if (tid == 0 && ((steps >> k) & 1)) sCenter = J[sCenter];
                if ((steps >> (k + 1)) != 0) {
                    __syncthreads();
                    for (int x = tid; x < Nn; x += 1024) J2[x] = J[J[x]];
                    __syncthreads();
                    unsigned short* t = J; J = J2; J2 = t;
                }
            }
            __syncthreads();
            curRoot = sCenter;
            rootC = curRoot;
        }
        __syncthreads();   // protect sPack/sR reset next round
    }
    const int D = (sPack >> 14) + 1;

    // ---- counting sort by depth (A free: scanS dead) ----
    unsigned short* posOf = (unsigned short*)A;        // [Nn]
    int* hist   = (int*)(A + 18432);                   // [2048]
    int* levOff = (int*)(A + 26624);                   // [2048]
    for (int k = tid; k < 2048; k += 1024) hist[k] = 0;
    __syncthreads();
    for (int v = tid; v < Nn; v += 1024) atomicAdd(&hist[depthB[v]], 1);
    __syncthreads();
    {
        int h0 = hist[2 * tid], h1 = hist[2 * tid + 1];
        int partial = h0 + h1;
        int incl = scan1024s(partial, tid, wsum);
        int eb = incl - partial;
        levOff[2 * tid] = eb;
        levOff[2 * tid + 1] = eb + h0;
    }
    __syncthreads();
    for (int d = tid; d <= D && d < 2048; d += 1024) levG[d] = levOff[d];
    for (int k = tid; k < 2048; k += 1024) hist[k] = 0;
    __syncthreads();
    for (int v = tid; v < Nn; v += 1024) {
        int dep = depthB[v];
        int pos = levOff[dep] + atomicAdd(&hist[dep], 1);
        posOf[v] = (unsigned short)pos;
        ordG[pos] = v;
    }
    __syncthreads();

    // ---- packed pair {w_bits, ppos} (parC rooted at center), batched ----
    {
        unsigned char rdA[9]; unsigned short posA[9];
        #pragma unroll
        for (int t = 0; t < 9; t++) {
            int v = tid + t * 1024;
            rdA[t] = parC[v]; posA[t] = posOf[v];
        }
        double ewv[9]; unsigned short ppv[9];
        #pragma unroll
        for (int t = 0; t < 9; t++) {
            int v = tid + t * 1024;
            int rd = rdA[t] & 3;
            bool ir = (v == rootC);
            int p  = ir ? v : v + dir_delta(rd);
            int ei = ir ? 0 : edge_of(v, rd);
            ppv[t] = posOf[p];
            ewv[t] = ew[ei];
        }
        #pragma unroll
        for (int t = 0; t < 9; t++) {
            int v = tid + t * 1024;
            int pos = posA[t];
            if (v == rootC) {
                pairG[pos] = make_uint2(0u, 0u);   // w=0.0f
            } else {
                float w = expf(-(float)ewv[t] * inv_sigma);
                pairG[pos] = make_uint2(__float_as_uint(w), (unsigned)ppv[t]);
            }
        }
    }
    if (tid == 0) dG[tb] = D;
}

// Single-wave two-pass tree DP — barrier-free, packed pair, R18 prefetch.
// The next level's pair loads issue into registers BEFORE the clobber, so
// the protected region's dependency chain is a single LDS round trip:
// up = read Al[i] -> ds_add; down = read Al[pp] -> fma -> write.
// Arithmetic/order identical to R15 (bit-exact). Wide levels (>64 nodes)
// fall back to in-level pair loads for the tail.
__global__ void __launch_bounds__(64)
k_dp(char* __restrict__ ws, int tree, int inMode) {
    const int bc = blockIdx.x;
    const int b = bc / NCh, c = bc % NCh;
    const int tb = tree * Bn + b;
    const int lane = threadIdx.x;
    const int*   ordG  = (const int*)(ws + OFF_ORD)  + (size_t)tb * Nn;
    const uint2* pairG = (const uint2*)(ws + OFF_PAIR) + (size_t)tb * Nn;
    const int*   levG  = (const int*)(ws + OFF_LEV)  + (size_t)tb * MAXD;
    const int D = ((const int*)(ws + OFF_D))[tb];
    const float* src = (inMode == 0)
        ? (const float*)(ws + OFF_PROB) + ((size_t)b * Cc + c) * Nn
        : (const float*)(ws + OFF_S1)   + ((size_t)b * NCh + c) * Nn;
    const float* srcN = (const float*)(ws + OFF_S1) + ((size_t)b * NCh + Cc) * Nn;
    float* dst = (float*)(ws + (tree ? OFF_S2 : OFF_S1)) + ((size_t)b * NCh + c) * Nn;

    __shared__ alignas(16) float Al[Nn];
    __shared__ alignas(16) uint2 pairS[Nn];
    __shared__ unsigned short levS[MAXD];

    // stage packed topology in LDS (vectorized, 2 pairs per uint4)
    {
        const uint4* pg4 = (const uint4*)pairG;
        uint4* ps4 = (uint4*)pairS;
        for (int k = lane; k < Nn / 2; k += 64) ps4[k] = pg4[k];
    }
    for (int d = lane; d <= D && d < MAXD; d += 64) levS[d] = (unsigned short)levG[d];
    if (c == Cc)            { for (int i = lane; i < Nn; i += 64) Al[i] = 1.0f; }
    else if (inMode == 0)   { for (int i = lane; i < Nn; i += 64) Al[i] = src[ordG[i]]; }
    else                    { for (int i = lane; i < Nn; i += 64) { int nd = ordG[i]; Al[i] = src[nd] / srcN[nd]; } }
    __builtin_amdgcn_wave_barrier();
    asm volatile("" ::: "memory");

    // up: children before parents (ds_add_f32 scatter), pair prefetched
    if (D > 1) {
        int sd = levS[D - 1], sd1 = levS[D];
        int pidx = sd + lane;
        uint2 pk = pairS[pidx < sd1 ? pidx : sd];
        for (int d = D - 1; d >= 1; d--) {
            int nbv = (d > 1) ? (int)levS[d - 1] : 0;
            // prefetch next level's pair (read-only array, off the chain)
            int nidx = nbv + lane;
            uint2 pk_next = pairS[(d > 1 && nidx < sd) ? nidx : 0];
            int i = sd + lane;
            if (i < sd1)
                atomicAdd(&Al[pk.y & 0x3FFFu], __uint_as_float(pk.x) * Al[i]);
            for (int j = i + 64; j < sd1; j += 64) {
                uint2 p2 = pairS[j];
                atomicAdd(&Al[p2.y & 0x3FFFu], __uint_as_float(p2.x) * Al[j]);
            }
            __builtin_amdgcn_wave_barrier();
            asm volatile("" ::: "memory");
            sd1 = sd; sd = nbv; pk = pk_next;
        }
    }
    // down: parents before children, pair prefetched
    if (D > 1) {
        int sd = levS[1], sd1 = levS[2];
        int pidx = sd + lane;
        uint2 pk = pairS[pidx < sd1 ? pidx : sd];
        for (int d = 1; d < D; d++) {
            int nbv = (d + 2 <= D) ? (int)levS[d + 2] : 0;
            // prefetch next level's pair (level d+1 spans [sd1, nbv))
            int nidx = sd1 + lane;
            uint2 pk_next = pairS[(d + 1 < D && nidx < nbv) ? nidx : 0];
            int i = sd + lane;
            if (i < sd1) {
                float w = __uint_as_float(pk.x);
                float a = Al[i];
                Al[i] = a + w * (Al[(int)(pk.y & 0x3FFFu)] - w * a);
            }
            for (int j = i + 64; j < sd1; j += 64) {
                uint2 p2 = pairS[j];
                float w = __uint_as_float(p2.x);
                float a = Al[j];
                Al[j] = a + w * (Al[(int)(p2.y & 0x3FFFu)] - w * a);
            }
            __builtin_amdgcn_wave_barrier();
            asm volatile("" ::: "memory");
            sd = sd1; sd1 = nbv; pk = pk_next;
        }
    }
    __builtin_amdgcn_wave_barrier();
    asm volatile("" ::: "memory");
    for (int i = lane; i < Nn; i += 64) dst[ordG[i]] = Al[i];
}

__global__ void k_loss(char* __restrict__ ws, const float* __restrict__ roi) {
    const int tid = threadIdx.x;
    int idx = blockIdx.x * 256 + tid;
    const float* prob = (const float*)(ws + OFF_PROB);
    const float* S2   = (const float*)(ws + OFF_S2);
    double* acc = (double*)(ws + OFF_ACC);
    double ls = 0.0, cnt = 0.0;
    if (idx < Bn * Cc * Nn) {
        int b = idx / (Cc * Nn);
        int rem = idx - b * (Cc * Nn);
        int c = rem / Nn, n = rem - c * Nn;
        int h = n / Ww, w2 = n - h * Ww;
        float r = roi[(size_t)b * (2 * Hh) * (2 * Ww) + (size_t)(2 * h) * (2 * Ww) + 2 * w2];
        float as = S2[((size_t)b * NCh + c) * Nn + n] / S2[((size_t)b * NCh + Cc) * Nn + n];
        float pp = prob[((size_t)b * Cc + c) * Nn + n];
        ls = (double)(r * fabsf(pp - as));
        if (c == 0) cnt = (double)r;
    }
    __shared__ double sl[256], sc2[256];
    sl[tid] = ls; sc2[tid] = cnt;
    __syncthreads();
    for (int s = 128; s > 0; s >>= 1) {
        if (tid < s) { sl[tid] += sl[tid + s]; sc2[tid] += sc2[tid + s]; }
        __syncthreads();
    }
    if (tid == 0) { atomicAdd(acc, sl[0]); atomicAdd(acc + 1, sc2[0]); }
}

__global__ void k_final(const double* __restrict__ acc, float* __restrict__ out) {
    if (blockIdx.x == 0 && threadIdx.x == 0)
        out[0] = (acc[1] > 0.0) ? (float)(acc[0] / acc[1]) : 0.0f;
}

extern "C" void kernel_launch(void* const* d_in, const int* in_sizes, int n_in,
                              void* d_out, int out_size, void* d_ws, size_t ws_size,
                              hipStream_t stream) {
    const float* preds = (const float*)d_in[0];
    const float* lowf  = (const float*)d_in[1];
    const float* highf = (const float*)d_in[2];
    const float* roi   = (const float*)d_in[3];
    char* ws = (char*)d_ws;
    float* out = (float*)d_out;
    double* ewl = (double*)(ws + OFF_EW);
    double* ewh = (double*)(ws + OFF_EW) + (size_t)Bn * Ne;

    k_init<<<(Bn * Cc * Nn + 255) / 256, 256, 0, stream>>>(
        preds, (float*)(ws + OFF_PROB), (double*)(ws + OFF_ACC));
    k_edgew<<<(Bn * Ne + 255) / 256, 256, 0, stream>>>(lowf, Clow, ewl);
    k_edgew<<<(Bn * Ne + 255) / 256, 256, 0, stream>>>(highf, Chigh, ewh);
    k_mst<<<8, 1024, 0, stream>>>(ws);
    k_topo<<<8, 1024, 0, stream>>>(ws);
    k_dp<<<Bn * NCh, 64, 0, stream>>>(ws, 0, 0);
    k_dp<<<Bn * NCh, 64, 0, stream>>>(ws, 1, 1);
    k_loss<<<(Bn * Cc * Nn + 255) / 256, 256, 0, stream>>>(ws, roi);
    k_final<<<1, 64, 0, stream>>>((const double*)(ws + OFF_ACC), out);
}

// Round 10
// 675.862 us; speedup vs baseline: 1.0682x; 1.0682x over previous
//
#include <hip/hip_runtime.h>
#include <math.h>
#include <stdint.h>
#include <stddef.h>

// TreeEnergyLoss on gfx950 — R19: R15 base (best known, 676.7us) +
// k_mst shfl-scan (saves ~160 16-wave barriers) + fused k_prep
// (k_init + 2x k_edgew, bit-identical per-element math, 2 fewer launches).
//
//  * k_dp: EXACT R15 (140.6us/dispatch floor — R14/R16/R17/R18 all showed
//    the level-synchronous single-wave chain is latency-irreducible).
//  * k_topo: R15 form unchanged.

namespace {
constexpr int Bn  = 4, Cc = 21, Hh = 96, Ww = 96;
constexpr int Nn  = Hh * Ww;              // 9216
constexpr int EhE = Hh * (Ww - 1);        // 9120
constexpr int Ne  = EhE + (Hh - 1) * Ww;  // 18240
constexpr int Clow = 3, Chigh = 512;
constexpr int NCh = Cc + 1;               // 22
constexpr int MAXD = 2048;
constexpr int TL  = 2 * (Nn - 1);         // 18430 arcs
constexpr int ESL = 18432;
constexpr int SEG = 19;                   // ruler stride (odd)
constexpr int NR  = (TL + SEG - 1) / SEG; // 970 rulers
constexpr int MAXC = 4608;
constexpr int NB_INIT = (Bn * Cc * Nn + 255) / 256;  // 3024
constexpr int NB_EDGE = (Bn * Ne + 255) / 256;       // 285

// workspace layout (bytes) — 16B-aligned
constexpr size_t OFF_ACC  = 0;                                        // 2 doubles
constexpr size_t OFF_PROB = 256;                                      // float[B][21][Nn]
constexpr size_t OFF_S1   = OFF_PROB + (size_t)Bn * Cc * Nn * 4;      // float[B][22][Nn]
constexpr size_t OFF_S2   = OFF_S1   + (size_t)Bn * NCh * Nn * 4;     // float[B][22][Nn]
constexpr size_t OFF_EW   = OFF_S2   + (size_t)Bn * NCh * Nn * 4;     // double[8][Ne]
constexpr size_t OFF_ORD  = OFF_EW   + (size_t)8 * Ne * 8;            // int[8][Nn]
constexpr size_t OFF_PPOS = OFF_ORD  + (size_t)8 * Nn * 4;            // (legacy, unused)
constexpr size_t OFF_WGT  = OFF_PPOS + (size_t)8 * Nn * 2;            // (k_mst EL2 overlay)
constexpr size_t OFF_LEV  = OFF_WGT  + (size_t)8 * Nn * 4;            // int[8][MAXD]
constexpr size_t OFF_D    = OFF_LEV  + (size_t)8 * MAXD * 4;          // int[8]
constexpr size_t OFF_DIR  = OFF_D    + 256;                           // int[8][Nn]
constexpr size_t OFF_CBW  = OFF_DIR  + (size_t)8 * Nn * 4;            // 73728 B/tb: elemSeg | ORG+OWNR
constexpr size_t OFF_CBE  = OFF_CBW  + (size_t)8 * Nn * 8;            // ushort[8][ESL] ownG
constexpr size_t OFF_OPP  = OFF_CBE  + (size_t)8 * Nn * 4;            // ushort[8][ESL] oppG
constexpr size_t OFF_SGN  = OFF_OPP  + (size_t)8 * ESL * 2;           // ushort[8][Nn] IRG
constexpr size_t OFF_PNF  = OFF_SGN  + (size_t)8 * ESL;               // uint[8][Nn] (unused)
constexpr size_t OFF_RNK  = OFF_PNF  + (size_t)8 * Nn * 4;            // ushort[8][ESL] rank0
constexpr size_t OFF_PAIR = OFF_RNK  + (size_t)8 * ESL * 2;           // uint2[8][Nn] {w_bits, ppos}
// k_mst edge-list ping/pong overlaid on regions dead until k_topo:
constexpr size_t OFF_EL1  = OFF_ORD;                                  // ushort[8][Ne]
constexpr size_t OFF_EL2  = OFF_WGT;                                  // ushort[8][Ne]
} // namespace

__device__ __forceinline__ void edge_nodes(int e, int& a, int& b) {
    if (e < EhE) { int h = e / (Ww - 1), w = e - h * (Ww - 1); a = h * Ww + w; b = a + 1; }
    else { int e2 = e - EhE; int h = e2 / Ww, w = e2 - h * Ww; a = h * Ww + w; b = a + Ww; }
}
// dirs: 0=E(+1) 1=W(-1) 2=S(+96) 3=N(-96); rev(d)=d^1
__device__ __forceinline__ int dir_delta(int d) {
    return (d == 0) ? 1 : (d == 1) ? -1 : (d == 2) ? Ww : -Ww;
}
__device__ __forceinline__ int edge_of(int u, int d) {
    int h = u / Ww, w = u - h * Ww;
    if (d == 0) return h * (Ww - 1) + w;
    if (d == 1) return h * (Ww - 1) + w - 1;
    if (d == 2) return EhE + u;
    return EhE + u - Ww;
}

// 64-bit total-order key: (fixed-point weight, edge index)
__device__ __forceinline__ unsigned long long mkkey(double w, int e) {
    unsigned long long q = (unsigned long long)(w * 70368744177664.0);  // 2^46
    if (q >= (1ull << 49)) q = (1ull << 49) - 1;
    return (q << 15) | (unsigned)e;
}

// wave-aggregated compaction push
__device__ __forceinline__ void compact_push(bool keep, int val, int* cnt,
                                             unsigned short* out, int lane) {
    unsigned long long m = __ballot(keep ? 1 : 0);
    if (m == 0ull) return;
    int leader = __ffsll((unsigned long long)m) - 1;
    int base = 0;
    if (lane == leader) base = atomicAdd(cnt, __popcll(m));
    base = __shfl(base, leader, 64);
    if (keep) {
        unsigned long long lower = m & ((1ull << lane) - 1ull);
        out[base + __popcll(lower)] = (unsigned short)val;
    }
}

// inclusive block scan (1024 threads = 16 waves) via shfl; wsum = int[16] LDS
__device__ __forceinline__ int scan1024s(int val, int tid, int* wsum) {
    __syncthreads();                      // protect wsum reuse
    int lane = tid & 63, wv = tid >> 6;
    int x = val;
    #pragma unroll
    for (int off = 1; off < 64; off <<= 1) {
        int y = __shfl_up(x, off, 64);
        if (lane >= off) x += y;
    }
    if (lane == 63) wsum[wv] = x;
    __syncthreads();
    if (wv == 0) {
        int s2 = (lane < 16) ? wsum[lane] : 0;
        #pragma unroll
        for (int off = 1; off < 16; off <<= 1) {
            int y = __shfl_up(s2, off, 64);
            if (lane >= off) s2 += y;
        }
        if (lane < 16) wsum[lane] = s2;
    }
    __syncthreads();
    int base = (wv > 0) ? wsum[wv - 1] : 0;
    return x + base;
}

// exact float64 edge weights, sequential channel order (bit-identical R11 body)
__device__ __forceinline__ void edgew_body(const float* __restrict__ feat, int C,
                                           double* __restrict__ ew, int idx) {
    if (idx >= Bn * Ne) return;
    int b = idx / Ne, e = idx - b * Ne;
    int a, c2; edge_nodes(e, a, c2);
    const float* fa = feat + (size_t)b * C * Nn + a;
    const float* fb = feat + (size_t)b * C * Nn + c2;
    double s = 0.0;
    int c = 0;
    for (; c + 16 <= C; c += 16) {
        float va[16], vb[16];
        #pragma unroll
        for (int k = 0; k < 16; k++) {
            va[k] = fa[(size_t)(c + k) * Nn];
            vb[k] = fb[(size_t)(c + k) * Nn];
        }
        #pragma unroll
        for (int k = 0; k < 16; k++) {
            double d = (double)va[k] - (double)vb[k];
            s += d * d;
        }
    }
    for (; c < C; c++) {
        double d = (double)fa[(size_t)c * Nn] - (double)fb[(size_t)c * Nn];
        s += d * d;
    }
    ew[idx] = s;
}

// Fused prologue: sigmoid + acc reset + both edge-weight passes (R19).
__global__ void k_prep(const float* __restrict__ preds,
                       const float* __restrict__ lowf,
                       const float* __restrict__ highf,
                       float* __restrict__ prob, double* __restrict__ acc,
                       double* __restrict__ ewl, double* __restrict__ ewh) {
    int bid = blockIdx.x;
    if (bid < NB_INIT) {
        int idx = bid * 256 + threadIdx.x;
        if (idx == 0) { acc[0] = 0.0; acc[1] = 0.0; }
        if (idx >= Bn * Cc * Nn) return;
        prob[idx] = 1.0f / (1.0f + expf(-preds[idx]));
    } else if (bid < NB_INIT + NB_EDGE) {
        int idx = (bid - NB_INIT) * 256 + threadIdx.x;
        edgew_body(lowf, Clow, ewl, idx);
    } else {
        int idx = (bid - NB_INIT - NB_EDGE) * 256 + threadIdx.x;
        edgew_body(highf, Chigh, ewh, idx);
    }
}

// Boruvka MST, LDS-resident (R8 core). R19: ladder scans -> shfl scans
// (same inclusive-scan values, ~7 fewer barriers per call).
__global__ void __launch_bounds__(1024)
k_mst(char* __restrict__ ws) {
    const int tb = blockIdx.x, tid = threadIdx.x;
    const int lane = tid & 63;
    const double* ew = (const double*)(ws + OFF_EW) + (size_t)tb * Ne;
    int* dirG = (int*)(ws + OFF_DIR) + (size_t)tb * Nn;
    unsigned short* elA = (unsigned short*)(ws + OFF_EL1) + (size_t)tb * Ne;
    unsigned short* elB = (unsigned short*)(ws + OFF_EL2) + (size_t)tb * Ne;

    __shared__ unsigned short comp[Nn];
    __shared__ unsigned long long cbK[MAXC];
    __shared__ int wsumM[16];
    __shared__ int chgArr[48];
    __shared__ int sLen, sNC;

    unsigned short* nxtN     = (unsigned short*)cbK;
    unsigned short* newSlotN = (unsigned short*)cbK + Nn;
    unsigned short* nxt      = (unsigned short*)cbK;
    unsigned short* newSlot  = (unsigned short*)cbK + MAXC;

    for (int i = tid; i < Nn; i += 1024) dirG[i] = 0;
    if (tid < 48) chgArr[tid] = 0;
    __syncthreads();

    for (int i = tid; i < Nn; i += 1024) {
        int h = i / Ww, w = i - h * Ww;
        unsigned long long bk = ~0ull;
        if (w < Ww - 1) { int e = h * (Ww - 1) + w;     unsigned long long k = mkkey(ew[e], e); if (k < bk) bk = k; }
        if (w > 0)      { int e = h * (Ww - 1) + w - 1; unsigned long long k = mkkey(ew[e], e); if (k < bk) bk = k; }
        if (h < Hh - 1) { int e = EhE + i;              unsigned long long k = mkkey(ew[e], e); if (k < bk) bk = k; }
        if (h > 0)      { int e = EhE + i - Ww;         unsigned long long k = mkkey(ew[e], e); if (k < bk) bk = k; }
        int e = (int)(bk & 0x7FFF);
        int a, c; edge_nodes(e, a, c);
        nxtN[i] = (unsigned short)((a == i) ? c : a);
        int da = (c == a + 1) ? 0 : 2;
        atomicOr(&dirG[a], 1 << da);
        atomicOr(&dirG[c], 1 << (da ^ 1));
    }
    __syncthreads();
    for (int i = tid; i < Nn; i += 1024) {
        int o = nxtN[i];
        if (o != i && nxtN[o] == i && i < o) nxtN[i] = (unsigned short)i;
    }
    __syncthreads();
    {
        int it = 0;
        while (it < 40) {
            bool any = false;
            for (int r = tid; r < Nn; r += 1024) {
                int nr = nxtN[r], nnr = nxtN[nr];
                if (nr != nnr) { nxtN[r] = (unsigned short)nnr; any = true; }
            }
            if (any) chgArr[it] = 1;
            __syncthreads();
            if (!chgArr[it]) break;
            it++;
        }
    }
    {
        int base = tid * 9, cnt = 0, loc[9];
        #pragma unroll
        for (int k = 0; k < 9; k++) {
            int i = base + k;
            loc[k] = cnt;
            if (nxtN[i] == i) cnt++;
        }
        int incl = scan1024s(cnt, tid, wsumM);
        int eb = incl - cnt;
        #pragma unroll
        for (int k = 0; k < 9; k++) {
            int i = base + k;
            if (nxtN[i] == i) newSlotN[i] = (unsigned short)(eb + loc[k]);
        }
        if (tid == 1023) sNC = incl;
    }
    __syncthreads();
    for (int i = tid; i < Nn; i += 1024) comp[i] = newSlotN[nxtN[i]];
    __syncthreads();
    int nComp = sNC;

    unsigned short* src = elA;
    unsigned short* dst = elB;
    int srcLen = -1;
    for (int round = 2; round < 22 && nComp > 1; round++) {
        if (tid == 0) sLen = 0;
        if (tid < 48) chgArr[tid] = 0;
        __syncthreads();
        if (srcLen < 0) {
            for (int e = tid; e < Ne; e += 1024) {
                int a, c; edge_nodes(e, a, c);
                compact_push(comp[a] != comp[c], e, &sLen, dst, lane);
            }
        } else {
            for (int k = tid; k < srcLen; k += 1024) {
                int e = src[k];
                int a, c; edge_nodes(e, a, c);
                compact_push(comp[a] != comp[c], e, &sLen, dst, lane);
            }
        }
        for (int s = tid; s < nComp; s += 1024) cbK[s] = ~0ull;
        __syncthreads();
        int len = sLen;
        if (len == 0) break;
        for (int k = tid; k < len; k += 1024) {
            int e = dst[k];
            int a, c; edge_nodes(e, a, c);
            unsigned long long key = mkkey(ew[e], e);
            atomicMin(&cbK[comp[a]], key);
            atomicMin(&cbK[comp[c]], key);
        }
        __syncthreads();
        unsigned long long kr[5];
        int nOwn = 0;
        for (int s = tid; s < nComp; s += 1024) kr[nOwn++] = cbK[s];
        __syncthreads();
        {
            int o = 0;
            for (int s = tid; s < nComp; s += 1024, o++) {
                unsigned long long key = kr[o];
                if (key != ~0ull) {
                    int e = (int)(key & 0x7FFF);
                    int a, c; edge_nodes(e, a, c);
                    int sa = comp[a], sc = comp[c];
                    nxt[s] = (unsigned short)((sa == s) ? sc : sa);
                    int da = (c == a + 1) ? 0 : 2;
                    atomicOr(&dirG[a], 1 << da);
                    atomicOr(&dirG[c], 1 << (da ^ 1));
                } else nxt[s] = (unsigned short)s;
            }
        }
        __syncthreads();
        for (int s = tid; s < nComp; s += 1024) {
            int o = nxt[s];
            if (o != s && nxt[o] == s && s < o) nxt[s] = (unsigned short)s;
        }
        __syncthreads();
        {
            int it = 0;
            while (it < 40) {
                bool any = false;
                for (int s = tid; s < nComp; s += 1024) {
                    int ns = nxt[s], nns = nxt[ns];
                    if (ns != nns) { nxt[s] = (unsigned short)nns; any = true; }
                }
                if (any) chgArr[it] = 1;
                __syncthreads();
                if (!chgArr[it]) break;
                it++;
            }
        }
        {
            int K = (nComp + 1023) >> 10;
            int base = tid * K, cnt = 0, loc[5];
            for (int k = 0; k < K; k++) {
                int s = base + k;
                loc[k] = cnt;
                if (s < nComp && nxt[s] == s) cnt++;
            }
            int incl = scan1024s(cnt, tid, wsumM);
            int eb = incl - cnt;
            for (int k = 0; k < K; k++) {
                int s = base + k;
                if (s < nComp && nxt[s] == s) newSlot[s] = (unsigned short)(eb + loc[k]);
            }
            if (tid == 1023) sNC = incl;
        }
        __syncthreads();
        for (int i = tid; i < Nn; i += 1024) comp[i] = newSlot[nxt[comp[i]]];
        __syncthreads();
        nComp = sNC;
        unsigned short* t = src; src = dst; dst = t;
        srcLen = len;
    }
}

// Euler-tour topology — R12 core: batched gathers + binary-lifting center walk.
// Final phase emits packed pairG {w_bits, ppos} (+ levG as before). (R15 form)
__global__ void __launch_bounds__(1024)
k_topo(char* __restrict__ ws) {
    const int tb = blockIdx.x, tid = threadIdx.x;
    const int lane = tid & 63, wv = tid >> 6;
    const int tree = tb >> 2;
    const double* ew  = (const double*)(ws + OFF_EW) + (size_t)tb * Ne;
    const int*  dirG  = (const int*)(ws + OFF_DIR) + (size_t)tb * Nn;
    unsigned int*   elemSegG = (unsigned int*)(ws + OFF_CBW + (size_t)tb * 73728);
    unsigned short* ORG      = (unsigned short*)(ws + OFF_CBW + (size_t)tb * 73728);      // after P4
    unsigned short* OWNR     = ORG + ESL;
    unsigned short* ownG     = (unsigned short*)(ws + OFF_CBE + (size_t)tb * (size_t)ESL * 2);
    unsigned short* oppG     = (unsigned short*)(ws + OFF_OPP + (size_t)tb * (size_t)ESL * 2);
    unsigned short* IRG      = (unsigned short*)(ws + OFF_SGN + (size_t)tb * ESL);
    unsigned short* rank0G   = (unsigned short*)(ws + OFF_RNK + (size_t)tb * (size_t)ESL * 2);
    int*            ordG  = (int*)(ws + OFF_ORD)  + (size_t)tb * Nn;
    uint2*          pairG = (uint2*)(ws + OFF_PAIR) + (size_t)tb * Nn;
    int*            levG  = (int*)(ws + OFF_LEV)  + (size_t)tb * MAXD;
    int*            dG    = (int*)(ws + OFF_D);
    const float inv_sigma = tree ? 1.0f : 50.0f;

    __shared__ char A[36864];   // nxtS | rulers(P3) | scanS | J-tables | final tables
    __shared__ char B[18432];   // degOff -> depthS
    __shared__ char C[9216];    // nbS -> parC
    __shared__ int  wsum[16];
    __shared__ int  sR, sPack, sCenter;

    // ---- P0: masks -> LDS; degree prefix sums ----
    unsigned short* degOff = (unsigned short*)B;
    unsigned char*  nbS    = (unsigned char*)C;
    for (int i = tid; i < Nn; i += 1024) nbS[i] = (unsigned char)dirG[i];
    __syncthreads();
    {
        int base9 = tid * 9;
        int loc[9]; int s = 0;
        #pragma unroll
        for (int k = 0; k < 9; k++) { loc[k] = s; s += __popc(nbS[base9 + k]); }
        int incl = scan1024s(s, tid, wsum);
        int eb = incl - s;
        #pragma unroll
        for (int k = 0; k < 9; k++) degOff[base9 + k] = (unsigned short)(eb + loc[k]);
    }
    __syncthreads();

    // ---- P1: Euler successor + owner + opposite ----
    unsigned short* nxtS = (unsigned short*)A;
    for (int u = tid; u < Nn; u += 1024) {
        int m = nbS[u]; int base = degOff[u]; int k = 0;
        #pragma unroll
        for (int d = 0; d < 4; d++) {
            if (m & (1 << d)) {
                int v = u + dir_delta(d);
                int mv = nbS[v]; int rd = d ^ 1;
                int pv = __popc(mv & ((1 << rd) - 1));
                int dv = __popc(mv);
                int nx = pv + 1; if (nx == dv) nx = 0;
                int j = base + k;
                nxtS[j] = (unsigned short)(degOff[v] + nx);
                ownG[j] = (unsigned short)((u << 2) | d);
                oppG[j] = (unsigned short)(degOff[v] + pv);
                k++;
            }
        }
    }
    __syncthreads();

    // ---- P2: ruling-set walks ----
    int myNr = 0, myLen = 0;
    if (tid < NR) {
        int x = tid * SEG, off = 0;
        for (int g = 0; g < 4096; g++) {
            elemSegG[x] = ((unsigned)tid << 11) | (unsigned)off;
            int y = nxtS[x];
            if (y % SEG == 0) { myNr = y / SEG; myLen = off + 1; break; }
            x = y; off++;
        }
    }
    __syncthreads();

    // ---- P3: ruler pointer doubling (rulers live in C; nbS dead) ----
    unsigned short* cn  = (unsigned short*)C;
    unsigned short* cd  = (unsigned short*)(C + 2048);
    unsigned short* nn2 = (unsigned short*)(C + 4096);
    unsigned short* nd2 = (unsigned short*)(C + 6144);
    if (tid == 0)      { cn[0] = 0; cd[0] = 0; }
    else if (tid < NR) { cn[tid] = (unsigned short)myNr; cd[tid] = (unsigned short)myLen; }
    else               { cn[tid] = (unsigned short)tid; cd[tid] = 0; }
    __syncthreads();
    for (int r = 0; r < 10; r++) {
        int c = cn[tid];
        int dv = cd[tid] + cd[c];
        int n2 = cn[c];
        nn2[tid] = (unsigned short)n2; nd2[tid] = (unsigned short)dv;
        __syncthreads();
        unsigned short* t;
        t = cn; cn = nn2; nn2 = t;
        t = cd; cd = nd2; nd2 = t;
    }
    unsigned short* rb = nn2;
    rb[tid] = (tid == 0) ? 0 : (unsigned short)(TL - cd[tid]);
    __syncthreads();

    // ---- P4: per-element rank0 (batched loads) ----
    for (int hh = 0; hh < 2; hh++) {
        unsigned int pk4[9];
        #pragma unroll
        for (int t = 0; t < 9; t++) {
            int e = tid + (hh * 9 + t) * 1024;
            pk4[t] = elemSegG[e < TL ? e : 0];
        }
        unsigned short rbv[9];
        #pragma unroll
        for (int t = 0; t < 9; t++) rbv[t] = rb[pk4[t] >> 11];
        #pragma unroll
        for (int t = 0; t < 9; t++) {
            int e = tid + (hh * 9 + t) * 1024;
            if (e < TL) rank0G[e] = (unsigned short)(rbv[t] + (pk4[t] & 2047));
        }
    }
    __syncthreads();

    // ---- P5: rank-space reindex (elemSegG dead -> ORG/OWNR), batched ----
    for (int hh = 0; hh < 2; hh++) {
        unsigned short rnk[9], opp[9], own2[9];
        #pragma unroll
        for (int t = 0; t < 9; t++) {
            int j = tid + (hh * 9 + t) * 1024;
            int ja = j < TL ? j : 0;
            rnk[t] = rank0G[ja]; opp[t] = oppG[ja]; own2[t] = ownG[ja];
        }
        unsigned short r2[9];
        #pragma unroll
        for (int t = 0; t < 9; t++) r2[t] = rank0G[opp[t]];
        #pragma unroll
        for (int t = 0; t < 9; t++) {
            int j = tid + (hh * 9 + t) * 1024;
            if (j < TL) { int r = rnk[t]; ORG[r] = r2[t]; OWNR[r] = own2[t]; }
        }
    }
    {
        unsigned short dof[9];
        #pragma unroll
        for (int t = 0; t < 9; t++) dof[t] = degOff[tid + t * 1024];
        unsigned short ov[9];
        #pragma unroll
        for (int t = 0; t < 9; t++) ov[t] = oppG[dof[t]];
        unsigned short rv[9];
        #pragma unroll
        for (int t = 0; t < 9; t++) rv[t] = rank0G[ov[t]];
        #pragma unroll
        for (int t = 0; t < 9; t++) IRG[tid + t * 1024] = rv[t];
    }
    __syncthreads();

    // ---- 3 rounds: root 0 -> u -> (v, diam, lifted walk->center) -> center emit ----
    short* scanS = (short*)A;                 // overlays nxtS (dead)
    unsigned char* parC = (unsigned char*)C;  // overlays rulers (dead)
    unsigned short* depthB = (unsigned short*)B;  // overlays degOff (dead after P5)
    int curRoot = 0, rootC = 0;
    for (int ph = 0; ph < 3; ph++) {
        if (tid == 0) {
            sR = ORG[IRG[curRoot]];   // rank0 of root's first out-arc
            sPack = 0;
        }
        __syncthreads();
        const int R = sR;
        const bool doPar = (ph >= 1);
        // fused sign+scan pass over rotated rank positions (batched loads)
        int base = tid * 18;
        int n = TL - base; if (n > 18) n = 18; if (n < 0) n = 0;
        unsigned short orvA[18], ownA[18];
        #pragma unroll
        for (int k = 0; k < 18; k++) {
            int q = base + k;
            int r = q + R; if (r >= TL) r -= TL; if (q >= TL) r = 0;
            orvA[k] = ORG[r];
        }
        if (doPar) {
            #pragma unroll
            for (int k = 0; k < 18; k++) {
                int q = base + k;
                int r = q + R; if (r >= TL) r -= TL; if (q >= TL) r = 0;
                ownA[k] = OWNR[r];
            }
        }
        short loc[18]; int s = 0;
        #pragma unroll
        for (int k = 0; k < 18; k++) {
            if (k < n) {
                int q = base + k;
                int rro = (int)orvA[k] - R; if (rro < 0) rro += TL;
                bool desc = q < rro;
                if (doPar && desc) {
                    int own = ownA[k];
                    int head = (own >> 2) + dir_delta(own & 3);
                    parC[head] = (unsigned char)((own & 3) ^ 1);
                }
                s += desc ? 1 : -1;
                loc[k] = (short)s;
            }
        }
        int incl = scan1024s(s, tid, wsum);
        int eb = incl - s;
        #pragma unroll
        for (int k = 0; k < 18; k++)
            if (k < n) scanS[base + k] = (short)(loc[k] + eb);
        __syncthreads();
        // depth gather (batched) + wave-reduced argmax
        int pk = 0;
        {
            unsigned short qA[9];
            #pragma unroll
            for (int j = 0; j < 9; j++) qA[j] = IRG[tid + j * 1024];
            int depA[9];
            #pragma unroll
            for (int j = 0; j < 9; j++) {
                int q = (int)qA[j] - R; if (q < 0) q += TL;
                depA[j] = (int)scanS[q];
            }
            #pragma unroll
            for (int j = 0; j < 9; j++) {
                int x = tid + j * 1024;
                int dep = (x == curRoot) ? 0 : depA[j];
                int p2 = (dep << 14) | x;
                if (p2 > pk) pk = p2;
                if (ph == 2) depthB[x] = (unsigned short)dep;
            }
        }
        #pragma unroll
        for (int off = 32; off > 0; off >>= 1) {
            int o = __shfl_down(pk, off, 64);
            if (o > pk) pk = o;
        }
        if (lane == 0) atomicMax(&sPack, pk);
        __syncthreads();
        if (ph == 0) curRoot = sPack & 16383;
        else if (ph == 1) {
            // binary-lifting walk: jump ceil(diam/2) parent-hops from v.
            // J tables overlay A (scanS dead until round 2 rebuilds it).
            int diam = sPack >> 14, v = sPack & 16383;
            int steps = diam - (diam >> 1);
            unsigned short* J  = (unsigned short*)A;
            unsigned short* J2 = (unsigned short*)(A + 18432);
            for (int x = tid; x < Nn; x += 1024)
                J[x] = (unsigned short)((x == curRoot) ? x : (x + dir_delta(parC[x])));
            if (tid == 0) sCenter = v;
            __syncthreads();
            for (int k = 0; (steps >> k) != 0; k++) {
                if (tid == 0 && ((steps >> k) & 1)) sCenter = J[sCenter];
                if ((steps >> (k + 1)) != 0) {
                    __syncthreads();
                    for (int x = tid; x < Nn; x += 1024) J2[x] = J[J[x]];
                    __syncthreads();
                    unsigned short* t = J; J = J2; J2 = t;
                }
            }
            __syncthreads();
            curRoot = sCenter;
            rootC = curRoot;
        }
        __syncthreads();   // protect sPack/sR reset next round
    }
    const int D = (sPack >> 14) + 1;

    // ---- counting sort by depth (A free: scanS dead) ----
    unsigned short* posOf = (unsigned short*)A;        // [Nn]
    int* hist   = (int*)(A + 18432);                   // [2048]
    int* levOff = (int*)(A + 26624);                   // [2048]
    for (int k = tid; k < 2048; k += 1024) hist[k] = 0;
    __syncthreads();
    for (int v = tid; v < Nn; v += 1024) atomicAdd(&hist[depthB[v]], 1);
    __syncthreads();
    {
        int h0 = hist[2 * tid], h1 = hist[2 * tid + 1];
        int partial = h0 + h1;
        int incl = scan1024s(partial, tid, wsum);
        int eb = incl - partial;
        levOff[2 * tid] = eb;
        levOff[2 * tid + 1] = eb + h0;
    }
    __syncthreads();
    for (int d = tid; d <= D && d < 2048; d += 1024) levG[d] = levOff[d];
    for (int k = tid; k < 2048; k += 1024) hist[k] = 0;
    __syncthreads();
    for (int v = tid; v < Nn; v += 1024) {
        int dep = depthB[v];
        int pos = levOff[dep] + atomicAdd(&hist[dep], 1);
        posOf[v] = (unsigned short)pos;
        ordG[pos] = v;
    }
    __syncthreads();

    // ---- packed pair {w_bits, ppos} (parC rooted at center), batched ----
    {
        unsigned char rdA[9]; unsigned short posA[9];
        #pragma unroll
        for (int t = 0; t < 9; t++) {
            int v = tid + t * 1024;
            rdA[t] = parC[v]; posA[t] = posOf[v];
        }
        double ewv[9]; unsigned short ppv[9];
        #pragma unroll
        for (int t = 0; t < 9; t++) {
            int v = tid + t * 1024;
            int rd = rdA[t] & 3;
            bool ir = (v == rootC);
            int p  = ir ? v : v + dir_delta(rd);
            int ei = ir ? 0 : edge_of(v, rd);
            ppv[t] = posOf[p];
            ewv[t] = ew[ei];
        }
        #pragma unroll
        for (int t = 0; t < 9; t++) {
            int v = tid + t * 1024;
            int pos = posA[t];
            if (v == rootC) {
                pairG[pos] = make_uint2(0u, 0u);   // w=0.0f
            } else {
                float w = expf(-(float)ewv[t] * inv_sigma);
                pairG[pos] = make_uint2(__float_as_uint(w), (unsigned)ppv[t]);
            }
        }
    }
    if (tid == 0) dG[tb] = D;
}

// Single-wave two-pass tree DP — barrier-free, packed pair (EXACT R15).
// Per level: up = {pair b64, Al[i] read, ds_add}; down = {pair b64, Al[i],
// Al[pp], write}. In-order DS pipe orders level d after level d+1/d-1 by
// program order; wave_barrier + memory clobber are compile-time-only fences.
__global__ void __launch_bounds__(64)
k_dp(char* __restrict__ ws, int tree, int inMode) {
    const int bc = blockIdx.x;
    const int b = bc / NCh, c = bc % NCh;
    const int tb = tree * Bn + b;
    const int lane = threadIdx.x;
    const int*   ordG  = (const int*)(ws + OFF_ORD)  + (size_t)tb * Nn;
    const uint2* pairG = (const uint2*)(ws + OFF_PAIR) + (size_t)tb * Nn;
    const int*   levG  = (const int*)(ws + OFF_LEV)  + (size_t)tb * MAXD;
    const int D = ((const int*)(ws + OFF_D))[tb];
    const float* src = (inMode == 0)
        ? (const float*)(ws + OFF_PROB) + ((size_t)b * Cc + c) * Nn
        : (const float*)(ws + OFF_S1)   + ((size_t)b * NCh + c) * Nn;
    const float* srcN = (const float*)(ws + OFF_S1) + ((size_t)b * NCh + Cc) * Nn;
    float* dst = (float*)(ws + (tree ? OFF_S2 : OFF_S1)) + ((size_t)b * NCh + c) * Nn;

    __shared__ alignas(16) float Al[Nn];
    __shared__ alignas(16) uint2 pairS[Nn];
    __shared__ unsigned short levS[MAXD];

    // stage packed topology in LDS (vectorized, 2 pairs per uint4)
    {
        const uint4* pg4 = (const uint4*)pairG;
        uint4* ps4 = (uint4*)pairS;
        for (int k = lane; k < Nn / 2; k += 64) ps4[k] = pg4[k];
    }
    for (int d = lane; d <= D && d < MAXD; d += 64) levS[d] = (unsigned short)levG[d];
    if (c == Cc)            { for (int i = lane; i < Nn; i += 64) Al[i] = 1.0f; }
    else if (inMode == 0)   { for (int i = lane; i < Nn; i += 64) Al[i] = src[ordG[i]]; }
    else                    { for (int i = lane; i < Nn; i += 64) { int nd = ordG[i]; Al[i] = src[nd] / srcN[nd]; } }
    __builtin_amdgcn_wave_barrier();
    asm volatile("" ::: "memory");

    // up: children before parents (ds_add_f32, no return)
    if (D > 1) {
        int sd = levS[D - 1], sd1 = levS[D];
        for (int d = D - 1; d >= 1; d--) {
            int nbv = (d > 1) ? (int)levS[d - 1] : 0;   // prefetch next boundary
            for (int i = sd + lane; i < sd1; i += 64) {
                uint2 pk = pairS[i];
                atomicAdd(&Al[pk.y], __uint_as_float(pk.x) * Al[i]);
            }
            __builtin_amdgcn_wave_barrier();
            asm volatile("" ::: "memory");
            sd1 = sd; sd = nbv;
        }
    }
    // down: parents before children
    if (D > 1) {
        int sd = levS[1], sd1 = levS[2];
        for (int d = 1; d < D; d++) {
            int nbv = (d + 2 <= D) ? (int)levS[d + 2] : 0;   // prefetch
            for (int i = sd + lane; i < sd1; i += 64) {
                uint2 pk = pairS[i];
                float w = __uint_as_float(pk.x);
                float a = Al[i];
                Al[i] = a + w * (Al[pk.y] - w * a);
            }
            __builtin_amdgcn_wave_barrier();
            asm volatile("" ::: "memory");
            sd = sd1; sd1 = nbv;
        }
    }
    __builtin_amdgcn_wave_barrier();
    asm volatile("" ::: "memory");
    for (int i = lane; i < Nn; i += 64) dst[ordG[i]] = Al[i];
}

__global__ void k_loss(char* __restrict__ ws, const float* __restrict__ roi) {
    const int tid = threadIdx.x;
    int idx = blockIdx.x * 256 + tid;
    const float* prob = (const float*)(ws + OFF_PROB);
    const float* S2   = (const float*)(ws + OFF_S2);
    double* acc = (double*)(ws + OFF_ACC);
    double ls = 0.0, cnt = 0.0;
    if (idx < Bn * Cc * Nn) {
        int b = idx / (Cc * Nn);
        int rem = idx - b * (Cc * Nn);
        int c = rem / Nn, n = rem - c * Nn;
        int h = n / Ww, w2 = n - h * Ww;
        float r = roi[(size_t)b * (2 * Hh) * (2 * Ww) + (size_t)(2 * h) * (2 * Ww) + 2 * w2];
        float as = S2[((size_t)b * NCh + c) * Nn + n] / S2[((size_t)b * NCh + Cc) * Nn + n];
        float pp = prob[((size_t)b * Cc + c) * Nn + n];
        ls = (double)(r * fabsf(pp - as));
        if (c == 0) cnt = (double)r;
    }
    __shared__ double sl[256], sc2[256];
    sl[tid] = ls; sc2[tid] = cnt;
    __syncthreads();
    for (int s = 128; s > 0; s >>= 1) {
        if (tid < s) { sl[tid] += sl[tid + s]; sc2[tid] += sc2[tid + s]; }
        __syncthreads();
    }
    if (tid == 0) { atomicAdd(acc, sl[0]); atomicAdd(acc + 1, sc2[0]); }
}

__global__ void k_final(const double* __restrict__ acc, float* __restrict__ out) {
    if (blockIdx.x == 0 && threadIdx.x == 0)
        out[0] = (acc[1] > 0.0) ? (float)(acc[0] / acc[1]) : 0.0f;
}

extern "C" void kernel_launch(void* const* d_in, const int* in_sizes, int n_in,
                              void* d_out, int out_size, void* d_ws, size_t ws_size,
                              hipStream_t stream) {
    const float* preds = (const float*)d_in[0];
    const float* lowf  = (const float*)d_in[1];
    const float* highf = (const float*)d_in[2];
    const float* roi   = (const float*)d_in[3];
    char* ws = (char*)d_ws;
    float* out = (float*)d_out;
    double* ewl = (double*)(ws + OFF_EW);
    double* ewh = (double*)(ws + OFF_EW) + (size_t)Bn * Ne;

    k_prep<<<NB_INIT + 2 * NB_EDGE, 256, 0, stream>>>(
        preds, lowf, highf, (float*)(ws + OFF_PROB), (double*)(ws + OFF_ACC),
        ewl, ewh);
    k_mst<<<8, 1024, 0, stream>>>(ws);
    k_topo<<<8, 1024, 0, stream>>>(ws);
    k_dp<<<Bn * NCh, 64, 0, stream>>>(ws, 0, 0);
    k_dp<<<Bn * NCh, 64, 0, stream>>>(ws, 1, 1);
    k_loss<<<(Bn * Cc * Nn + 255) / 256, 256, 0, stream>>>(ws, roi);
    k_final<<<1, 64, 0, stream>>>((const double*)(ws + OFF_ACC), out);
}

// Round 11
// 659.070 us; speedup vs baseline: 1.0954x; 1.0255x over previous
//
#include <hip/hip_runtime.h>
#include <math.h>
#include <stdint.h>
#include <stddef.h>

// TreeEnergyLoss on gfx950 — R20: R19 base, k_dp per-level fences removed.
//
//  * The per-level wave_barrier+memory-clobber was redundant for
//    correctness: all Al[] accesses may-alias (runtime indices), so the
//    compiler preserves their program order; the single-wave in-order DS
//    queue preserves it in hardware. The fences only forced pairS/levS
//    reads + loop scaffolding back onto the serial chain each level.
//    Removing them lets the scheduler hoist/pipeline the no-alias arrays
//    (pairS, levS are distinct __shared__ objects) across levels.
//  * Arithmetic/op order on Al identical to R15/R19 -> bit-exact.
//  * Everything else: exact R19 (k_prep fusion, k_mst shfl-scan, R12 k_topo).

namespace {
constexpr int Bn  = 4, Cc = 21, Hh = 96, Ww = 96;
constexpr int Nn  = Hh * Ww;              // 9216
constexpr int EhE = Hh * (Ww - 1);        // 9120
constexpr int Ne  = EhE + (Hh - 1) * Ww;  // 18240
constexpr int Clow = 3, Chigh = 512;
constexpr int NCh = Cc + 1;               // 22
constexpr int MAXD = 2048;
constexpr int TL  = 2 * (Nn - 1);         // 18430 arcs
constexpr int ESL = 18432;
constexpr int SEG = 19;                   // ruler stride (odd)
constexpr int NR  = (TL + SEG - 1) / SEG; // 970 rulers
constexpr int MAXC = 4608;
constexpr int NB_INIT = (Bn * Cc * Nn + 255) / 256;  // 3024
constexpr int NB_EDGE = (Bn * Ne + 255) / 256;       // 285

// workspace layout (bytes) — 16B-aligned
constexpr size_t OFF_ACC  = 0;                                        // 2 doubles
constexpr size_t OFF_PROB = 256;                                      // float[B][21][Nn]
constexpr size_t OFF_S1   = OFF_PROB + (size_t)Bn * Cc * Nn * 4;      // float[B][22][Nn]
constexpr size_t OFF_S2   = OFF_S1   + (size_t)Bn * NCh * Nn * 4;     // float[B][22][Nn]
constexpr size_t OFF_EW   = OFF_S2   + (size_t)Bn * NCh * Nn * 4;     // double[8][Ne]
constexpr size_t OFF_ORD  = OFF_EW   + (size_t)8 * Ne * 8;            // int[8][Nn]
constexpr size_t OFF_PPOS = OFF_ORD  + (size_t)8 * Nn * 4;            // (legacy, unused)
constexpr size_t OFF_WGT  = OFF_PPOS + (size_t)8 * Nn * 2;            // (k_mst EL2 overlay)
constexpr size_t OFF_LEV  = OFF_WGT  + (size_t)8 * Nn * 4;            // int[8][MAXD]
constexpr size_t OFF_D    = OFF_LEV  + (size_t)8 * MAXD * 4;          // int[8]
constexpr size_t OFF_DIR  = OFF_D    + 256;                           // int[8][Nn]
constexpr size_t OFF_CBW  = OFF_DIR  + (size_t)8 * Nn * 4;            // 73728 B/tb: elemSeg | ORG+OWNR
constexpr size_t OFF_CBE  = OFF_CBW  + (size_t)8 * Nn * 8;            // ushort[8][ESL] ownG
constexpr size_t OFF_OPP  = OFF_CBE  + (size_t)8 * Nn * 4;            // ushort[8][ESL] oppG
constexpr size_t OFF_SGN  = OFF_OPP  + (size_t)8 * ESL * 2;           // ushort[8][Nn] IRG
constexpr size_t OFF_PNF  = OFF_SGN  + (size_t)8 * ESL;               // uint[8][Nn] (unused)
constexpr size_t OFF_RNK  = OFF_PNF  + (size_t)8 * Nn * 4;            // ushort[8][ESL] rank0
constexpr size_t OFF_PAIR = OFF_RNK  + (size_t)8 * ESL * 2;           // uint2[8][Nn] {w_bits, ppos}
// k_mst edge-list ping/pong overlaid on regions dead until k_topo:
constexpr size_t OFF_EL1  = OFF_ORD;                                  // ushort[8][Ne]
constexpr size_t OFF_EL2  = OFF_WGT;                                  // ushort[8][Ne]
} // namespace

__device__ __forceinline__ void edge_nodes(int e, int& a, int& b) {
    if (e < EhE) { int h = e / (Ww - 1), w = e - h * (Ww - 1); a = h * Ww + w; b = a + 1; }
    else { int e2 = e - EhE; int h = e2 / Ww, w = e2 - h * Ww; a = h * Ww + w; b = a + Ww; }
}
// dirs: 0=E(+1) 1=W(-1) 2=S(+96) 3=N(-96); rev(d)=d^1
__device__ __forceinline__ int dir_delta(int d) {
    return (d == 0) ? 1 : (d == 1) ? -1 : (d == 2) ? Ww : -Ww;
}
__device__ __forceinline__ int edge_of(int u, int d) {
    int h = u / Ww, w = u - h * Ww;
    if (d == 0) return h * (Ww - 1) + w;
    if (d == 1) return h * (Ww - 1) + w - 1;
    if (d == 2) return EhE + u;
    return EhE + u - Ww;
}

// 64-bit total-order key: (fixed-point weight, edge index)
__device__ __forceinline__ unsigned long long mkkey(double w, int e) {
    unsigned long long q = (unsigned long long)(w * 70368744177664.0);  // 2^46
    if (q >= (1ull << 49)) q = (1ull << 49) - 1;
    return (q << 15) | (unsigned)e;
}

// wave-aggregated compaction push
__device__ __forceinline__ void compact_push(bool keep, int val, int* cnt,
                                             unsigned short* out, int lane) {
    unsigned long long m = __ballot(keep ? 1 : 0);
    if (m == 0ull) return;
    int leader = __ffsll((unsigned long long)m) - 1;
    int base = 0;
    if (lane == leader) base = atomicAdd(cnt, __popcll(m));
    base = __shfl(base, leader, 64);
    if (keep) {
        unsigned long long lower = m & ((1ull << lane) - 1ull);
        out[base + __popcll(lower)] = (unsigned short)val;
    }
}

// inclusive block scan (1024 threads = 16 waves) via shfl; wsum = int[16] LDS
__device__ __forceinline__ int scan1024s(int val, int tid, int* wsum) {
    __syncthreads();                      // protect wsum reuse
    int lane = tid & 63, wv = tid >> 6;
    int x = val;
    #pragma unroll
    for (int off = 1; off < 64; off <<= 1) {
        int y = __shfl_up(x, off, 64);
        if (lane >= off) x += y;
    }
    if (lane == 63) wsum[wv] = x;
    __syncthreads();
    if (wv == 0) {
        int s2 = (lane < 16) ? wsum[lane] : 0;
        #pragma unroll
        for (int off = 1; off < 16; off <<= 1) {
            int y = __shfl_up(s2, off, 64);
            if (lane >= off) s2 += y;
        }
        if (lane < 16) wsum[lane] = s2;
    }
    __syncthreads();
    int base = (wv > 0) ? wsum[wv - 1] : 0;
    return x + base;
}

// exact float64 edge weights, sequential channel order (bit-identical R11 body)
__device__ __forceinline__ void edgew_body(const float* __restrict__ feat, int C,
                                           double* __restrict__ ew, int idx) {
    if (idx >= Bn * Ne) return;
    int b = idx / Ne, e = idx - b * Ne;
    int a, c2; edge_nodes(e, a, c2);
    const float* fa = feat + (size_t)b * C * Nn + a;
    const float* fb = feat + (size_t)b * C * Nn + c2;
    double s = 0.0;
    int c = 0;
    for (; c + 16 <= C; c += 16) {
        float va[16], vb[16];
        #pragma unroll
        for (int k = 0; k < 16; k++) {
            va[k] = fa[(size_t)(c + k) * Nn];
            vb[k] = fb[(size_t)(c + k) * Nn];
        }
        #pragma unroll
        for (int k = 0; k < 16; k++) {
            double d = (double)va[k] - (double)vb[k];
            s += d * d;
        }
    }
    for (; c < C; c++) {
        double d = (double)fa[(size_t)c * Nn] - (double)fb[(size_t)c * Nn];
        s += d * d;
    }
    ew[idx] = s;
}

// Fused prologue: sigmoid + acc reset + both edge-weight passes (R19).
__global__ void k_prep(const float* __restrict__ preds,
                       const float* __restrict__ lowf,
                       const float* __restrict__ highf,
                       float* __restrict__ prob, double* __restrict__ acc,
                       double* __restrict__ ewl, double* __restrict__ ewh) {
    int bid = blockIdx.x;
    if (bid < NB_INIT) {
        int idx = bid * 256 + threadIdx.x;
        if (idx == 0) { acc[0] = 0.0; acc[1] = 0.0; }
        if (idx >= Bn * Cc * Nn) return;
        prob[idx] = 1.0f / (1.0f + expf(-preds[idx]));
    } else if (bid < NB_INIT + NB_EDGE) {
        int idx = (bid - NB_INIT) * 256 + threadIdx.x;
        edgew_body(lowf, Clow, ewl, idx);
    } else {
        int idx = (bid - NB_INIT - NB_EDGE) * 256 + threadIdx.x;
        edgew_body(highf, Chigh, ewh, idx);
    }
}

// Boruvka MST, LDS-resident (R8 core). R19: ladder scans -> shfl scans.
__global__ void __launch_bounds__(1024)
k_mst(char* __restrict__ ws) {
    const int tb = blockIdx.x, tid = threadIdx.x;
    const int lane = tid & 63;
    const double* ew = (const double*)(ws + OFF_EW) + (size_t)tb * Ne;
    int* dirG = (int*)(ws + OFF_DIR) + (size_t)tb * Nn;
    unsigned short* elA = (unsigned short*)(ws + OFF_EL1) + (size_t)tb * Ne;
    unsigned short* elB = (unsigned short*)(ws + OFF_EL2) + (size_t)tb * Ne;

    __shared__ unsigned short comp[Nn];
    __shared__ unsigned long long cbK[MAXC];
    __shared__ int wsumM[16];
    __shared__ int chgArr[48];
    __shared__ int sLen, sNC;

    unsigned short* nxtN     = (unsigned short*)cbK;
    unsigned short* newSlotN = (unsigned short*)cbK + Nn;
    unsigned short* nxt      = (unsigned short*)cbK;
    unsigned short* newSlot  = (unsigned short*)cbK + MAXC;

    for (int i = tid; i < Nn; i += 1024) dirG[i] = 0;
    if (tid < 48) chgArr[tid] = 0;
    __syncthreads();

    for (int i = tid; i < Nn; i += 1024) {
        int h = i / Ww, w = i - h * Ww;
        unsigned long long bk = ~0ull;
        if (w < Ww - 1) { int e = h * (Ww - 1) + w;     unsigned long long k = mkkey(ew[e], e); if (k < bk) bk = k; }
        if (w > 0)      { int e = h * (Ww - 1) + w - 1; unsigned long long k = mkkey(ew[e], e); if (k < bk) bk = k; }
        if (h < Hh - 1) { int e = EhE + i;              unsigned long long k = mkkey(ew[e], e); if (k < bk) bk = k; }
        if (h > 0)      { int e = EhE + i - Ww;         unsigned long long k = mkkey(ew[e], e); if (k < bk) bk = k; }
        int e = (int)(bk & 0x7FFF);
        int a, c; edge_nodes(e, a, c);
        nxtN[i] = (unsigned short)((a == i) ? c : a);
        int da = (c == a + 1) ? 0 : 2;
        atomicOr(&dirG[a], 1 << da);
        atomicOr(&dirG[c], 1 << (da ^ 1));
    }
    __syncthreads();
    for (int i = tid; i < Nn; i += 1024) {
        int o = nxtN[i];
        if (o != i && nxtN[o] == i && i < o) nxtN[i] = (unsigned short)i;
    }
    __syncthreads();
    {
        int it = 0;
        while (it < 40) {
            bool any = false;
            for (int r = tid; r < Nn; r += 1024) {
                int nr = nxtN[r], nnr = nxtN[nr];
                if (nr != nnr) { nxtN[r] = (unsigned short)nnr; any = true; }
            }
            if (any) chgArr[it] = 1;
            __syncthreads();
            if (!chgArr[it]) break;
            it++;
        }
    }
    {
        int base = tid * 9, cnt = 0, loc[9];
        #pragma unroll
        for (int k = 0; k < 9; k++) {
            int i = base + k;
            loc[k] = cnt;
            if (nxtN[i] == i) cnt++;
        }
        int incl = scan1024s(cnt, tid, wsumM);
        int eb = incl - cnt;
        #pragma unroll
        for (int k = 0; k < 9; k++) {
            int i = base + k;
            if (nxtN[i] == i) newSlotN[i] = (unsigned short)(eb + loc[k]);
        }
        if (tid == 1023) sNC = incl;
    }
    __syncthreads();
    for (int i = tid; i < Nn; i += 1024) comp[i] = newSlotN[nxtN[i]];
    __syncthreads();
    int nComp = sNC;

    unsigned short* src = elA;
    unsigned short* dst = elB;
    int srcLen = -1;
    for (int round = 2; round < 22 && nComp > 1; round++) {
        if (tid == 0) sLen = 0;
        if (tid < 48) chgArr[tid] = 0;
        __syncthreads();
        if (srcLen < 0) {
            for (int e = tid; e < Ne; e += 1024) {
                int a, c; edge_nodes(e, a, c);
                compact_push(comp[a] != comp[c], e, &sLen, dst, lane);
            }
        } else {
            for (int k = tid; k < srcLen; k += 1024) {
                int e = src[k];
                int a, c; edge_nodes(e, a, c);
                compact_push(comp[a] != comp[c], e, &sLen, dst, lane);
            }
        }
        for (int s = tid; s < nComp; s += 1024) cbK[s] = ~0ull;
        __syncthreads();
        int len = sLen;
        if (len == 0) break;
        for (int k = tid; k < len; k += 1024) {
            int e = dst[k];
            int a, c; edge_nodes(e, a, c);
            unsigned long long key = mkkey(ew[e], e);
            atomicMin(&cbK[comp[a]], key);
            atomicMin(&cbK[comp[c]], key);
        }
        __syncthreads();
        unsigned long long kr[5];
        int nOwn = 0;
        for (int s = tid; s < nComp; s += 1024) kr[nOwn++] = cbK[s];
        __syncthreads();
        {
            int o = 0;
            for (int s = tid; s < nComp; s += 1024, o++) {
                unsigned long long key = kr[o];
                if (key != ~0ull) {
                    int e = (int)(key & 0x7FFF);
                    int a, c; edge_nodes(e, a, c);
                    int sa = comp[a], sc = comp[c];
                    nxt[s] = (unsigned short)((sa == s) ? sc : sa);
                    int da = (c == a + 1) ? 0 : 2;
                    atomicOr(&dirG[a], 1 << da);
                    atomicOr(&dirG[c], 1 << (da ^ 1));
                } else nxt[s] = (unsigned short)s;
            }
        }
        __syncthreads();
        for (int s = tid; s < nComp; s += 1024) {
            int o = nxt[s];
            if (o != s && nxt[o] == s && s < o) nxt[s] = (unsigned short)s;
        }
        __syncthreads();
        {
            int it = 0;
            while (it < 40) {
                bool any = false;
                for (int s = tid; s < nComp; s += 1024) {
                    int ns = nxt[s], nns = nxt[ns];
                    if (ns != nns) { nxt[s] = (unsigned short)nns; any = true; }
                }
                if (any) chgArr[it] = 1;
                __syncthreads();
                if (!chgArr[it]) break;
                it++;
            }
        }
        {
            int K = (nComp + 1023) >> 10;
            int base = tid * K, cnt = 0, loc[5];
            for (int k = 0; k < K; k++) {
                int s = base + k;
                loc[k] = cnt;
                if (s < nComp && nxt[s] == s) cnt++;
            }
            int incl = scan1024s(cnt, tid, wsumM);
            int eb = incl - cnt;
            for (int k = 0; k < K; k++) {
                int s = base + k;
                if (s < nComp && nxt[s] == s) newSlot[s] = (unsigned short)(eb + loc[k]);
            }
            if (tid == 1023) sNC = incl;
        }
        __syncthreads();
        for (int i = tid; i < Nn; i += 1024) comp[i] = newSlot[nxt[comp[i]]];
        __syncthreads();
        nComp = sNC;
        unsigned short* t = src; src = dst; dst = t;
        srcLen = len;
    }
}

// Euler-tour topology — R12 core: batched gathers + binary-lifting center walk.
// Final phase emits packed pairG {w_bits, ppos} (+ levG as before). (R15 form)
__global__ void __launch_bounds__(1024)
k_topo(char* __restrict__ ws) {
    const int tb = blockIdx.x, tid = threadIdx.x;
    const int lane = tid & 63, wv = tid >> 6;
    const int tree = tb >> 2;
    const double* ew  = (const double*)(ws + OFF_EW) + (size_t)tb * Ne;
    const int*  dirG  = (const int*)(ws + OFF_DIR) + (size_t)tb * Nn;
    unsigned int*   elemSegG = (unsigned int*)(ws + OFF_CBW + (size_t)tb * 73728);
    unsigned short* ORG      = (unsigned short*)(ws + OFF_CBW + (size_t)tb * 73728);      // after P4
    unsigned short* OWNR     = ORG + ESL;
    unsigned short* ownG     = (unsigned short*)(ws + OFF_CBE + (size_t)tb * (size_t)ESL * 2);
    unsigned short* oppG     = (unsigned short*)(ws + OFF_OPP + (size_t)tb * (size_t)ESL * 2);
    unsigned short* IRG      = (unsigned short*)(ws + OFF_SGN + (size_t)tb * ESL);
    unsigned short* rank0G   = (unsigned short*)(ws + OFF_RNK + (size_t)tb * (size_t)ESL * 2);
    int*            ordG  = (int*)(ws + OFF_ORD)  + (size_t)tb * Nn;
    uint2*          pairG = (uint2*)(ws + OFF_PAIR) + (size_t)tb * Nn;
    int*            levG  = (int*)(ws + OFF_LEV)  + (size_t)tb * MAXD;
    int*            dG    = (int*)(ws + OFF_D);
    const float inv_sigma = tree ? 1.0f : 50.0f;

    __shared__ char A[36864];   // nxtS | rulers(P3) | scanS | J-tables | final tables
    __shared__ char B[18432];   // degOff -> depthS
    __shared__ char C[9216];    // nbS -> parC
    __shared__ int  wsum[16];
    __shared__ int  sR, sPack, sCenter;

    // ---- P0: masks -> LDS; degree prefix sums ----
    unsigned short* degOff = (unsigned short*)B;
    unsigned char*  nbS    = (unsigned char*)C;
    for (int i = tid; i < Nn; i += 1024) nbS[i] = (unsigned char)dirG[i];
    __syncthreads();
    {
        int base9 = tid * 9;
        int loc[9]; int s = 0;
        #pragma unroll
        for (int k = 0; k < 9; k++) { loc[k] = s; s += __popc(nbS[base9 + k]); }
        int incl = scan1024s(s, tid, wsum);
        int eb = incl - s;
        #pragma unroll
        for (int k = 0; k < 9; k++) degOff[base9 + k] = (unsigned short)(eb + loc[k]);
    }
    __syncthreads();

    // ---- P1: Euler successor + owner + opposite ----
    unsigned short* nxtS = (unsigned short*)A;
    for (int u = tid; u < Nn; u += 1024) {
        int m = nbS[u]; int base = degOff[u]; int k = 0;
        #pragma unroll
        for (int d = 0; d < 4; d++) {
            if (m & (1 << d)) {
                int v = u + dir_delta(d);
                int mv = nbS[v]; int rd = d ^ 1;
                int pv = __popc(mv & ((1 << rd) - 1));
                int dv = __popc(mv);
                int nx = pv + 1; if (nx == dv) nx = 0;
                int j = base + k;
                nxtS[j] = (unsigned short)(degOff[v] + nx);
                ownG[j] = (unsigned short)((u << 2) | d);
                oppG[j] = (unsigned short)(degOff[v] + pv);
                k++;
            }
        }
    }
    __syncthreads();

    // ---- P2: ruling-set walks ----
    int myNr = 0, myLen = 0;
    if (tid < NR) {
        int x = tid * SEG, off = 0;
        for (int g = 0; g < 4096; g++) {
            elemSegG[x] = ((unsigned)tid << 11) | (unsigned)off;
            int y = nxtS[x];
            if (y % SEG == 0) { myNr = y / SEG; myLen = off + 1; break; }
            x = y; off++;
        }
    }
    __syncthreads();

    // ---- P3: ruler pointer doubling (rulers live in C; nbS dead) ----
    unsigned short* cn  = (unsigned short*)C;
    unsigned short* cd  = (unsigned short*)(C + 2048);
    unsigned short* nn2 = (unsigned short*)(C + 4096);
    unsigned short* nd2 = (unsigned short*)(C + 6144);
    if (tid == 0)      { cn[0] = 0; cd[0] = 0; }
    else if (tid < NR) { cn[tid] = (unsigned short)myNr; cd[tid] = (unsigned short)myLen; }
    else               { cn[tid] = (unsigned short)tid; cd[tid] = 0; }
    __syncthreads();
    for (int r = 0; r < 10; r++) {
        int c = cn[tid];
        int dv = cd[tid] + cd[c];
        int n2 = cn[c];
        nn2[tid] = (unsigned short)n2; nd2[tid] = (unsigned short)dv;
        __syncthreads();
        unsigned short* t;
        t = cn; cn = nn2; nn2 = t;
        t = cd; cd = nd2; nd2 = t;
    }
    unsigned short* rb = nn2;
    rb[tid] = (tid == 0) ? 0 : (unsigned short)(TL - cd[tid]);
    __syncthreads();

    // ---- P4: per-element rank0 (batched loads) ----
    for (int hh = 0; hh < 2; hh++) {
        unsigned int pk4[9];
        #pragma unroll
        for (int t = 0; t < 9; t++) {
            int e = tid + (hh * 9 + t) * 1024;
            pk4[t] = elemSegG[e < TL ? e : 0];
        }
        unsigned short rbv[9];
        #pragma unroll
        for (int t = 0; t < 9; t++) rbv[t] = rb[pk4[t] >> 11];
        #pragma unroll
        for (int t = 0; t < 9; t++) {
            int e = tid + (hh * 9 + t) * 1024;
            if (e < TL) rank0G[e] = (unsigned short)(rbv[t] + (pk4[t] & 2047));
        }
    }
    __syncthreads();

    // ---- P5: rank-space reindex (elemSegG dead -> ORG/OWNR), batched ----
    for (int hh = 0; hh < 2; hh++) {
        unsigned short rnk[9], opp[9], own2[9];
        #pragma unroll
        for (int t = 0; t < 9; t++) {
            int j = tid + (hh * 9 + t) * 1024;
            int ja = j < TL ? j : 0;
            rnk[t] = rank0G[ja]; opp[t] = oppG[ja]; own2[t] = ownG[ja];
        }
        unsigned short r2[9];
        #pragma unroll
        for (int t = 0; t < 9; t++) r2[t] = rank0G[opp[t]];
        #pragma unroll
        for (int t = 0; t < 9; t++) {
            int j = tid + (hh * 9 + t) * 1024;
            if (j < TL) { int r = rnk[t]; ORG[r] = r2[t]; OWNR[r] = own2[t]; }
        }
    }
    {
        unsigned short dof[9];
        #pragma unroll
        for (int t = 0; t < 9; t++) dof[t] = degOff[tid + t * 1024];
        unsigned short ov[9];
        #pragma unroll
        for (int t = 0; t < 9; t++) ov[t] = oppG[dof[t]];
        unsigned short rv[9];
        #pragma unroll
        for (int t = 0; t < 9; t++) rv[t] = rank0G[ov[t]];
        #pragma unroll
        for (int t = 0; t < 9; t++) IRG[tid + t * 1024] = rv[t];
    }
    __syncthreads();

    // ---- 3 rounds: root 0 -> u -> (v, diam, lifted walk->center) -> center emit ----
    short* scanS = (short*)A;                 // overlays nxtS (dead)
    unsigned char* parC = (unsigned char*)C;  // overlays rulers (dead)
    unsigned short* depthB = (unsigned short*)B;  // overlays degOff (dead after P5)
    int curRoot = 0, rootC = 0;
    for (int ph = 0; ph < 3; ph++) {
        if (tid == 0) {
            sR = ORG[IRG[curRoot]];   // rank0 of root's first out-arc
            sPack = 0;
        }
        __syncthreads();
        const int R = sR;
        const bool doPar = (ph >= 1);
        // fused sign+scan pass over rotated rank positions (batched loads)
        int base = tid * 18;
        int n = TL - base; if (n > 18) n = 18; if (n < 0) n = 0;
        unsigned short orvA[18], ownA[18];
        #pragma unroll
        for (int k = 0; k < 18; k++) {
            int q = base + k;
            int r = q + R; if (r >= TL) r -= TL; if (q >= TL) r = 0;
            orvA[k] = ORG[r];
        }
        if (doPar) {
            #pragma unroll
            for (int k = 0; k < 18; k++) {
                int q = base + k;
                int r = q + R; if (r >= TL) r -= TL; if (q >= TL) r = 0;
                ownA[k] = OWNR[r];
            }
        }
        short loc[18]; int s = 0;
        #pragma unroll
        for (int k = 0; k < 18; k++) {
            if (k < n) {
                int q = base + k;
                int rro = (int)orvA[k] - R; if (rro < 0) rro += TL;
                bool desc = q < rro;
                if (doPar && desc) {
                    int own = ownA[k];
                    int head = (own >> 2) + dir_delta(own & 3);
                    parC[head] = (unsigned char)((own & 3) ^ 1);
                }
                s += desc ? 1 : -1;
                loc[k] = (short)s;
            }
        }
        int incl = scan1024s(s, tid, wsum);
        int eb = incl - s;
        #pragma unroll
        for (int k = 0; k < 18; k++)
            if (k < n) scanS[base + k] = (short)(loc[k] + eb);
        __syncthreads();
        // depth gather (batched) + wave-reduced argmax
        int pk = 0;
        {
            unsigned short qA[9];
            #pragma unroll
            for (int j = 0; j < 9; j++) qA[j] = IRG[tid + j * 1024];
            int depA[9];
            #pragma unroll
            for (int j = 0; j < 9; j++) {
                int q = (int)qA[j] - R; if (q < 0) q += TL;
                depA[j] = (int)scanS[q];
            }
            #pragma unroll
            for (int j = 0; j < 9; j++) {
                int x = tid + j * 1024;
                int dep = (x == curRoot) ? 0 : depA[j];
                int p2 = (dep << 14) | x;
                if (p2 > pk) pk = p2;
                if (ph == 2) depthB[x] = (unsigned short)dep;
            }
        }
        #pragma unroll
        for (int off = 32; off > 0; off >>= 1) {
            int o = __shfl_down(pk, off, 64);
            if (o > pk) pk = o;
        }
        if (lane == 0) atomicMax(&sPack, pk);
        __syncthreads();
        if (ph == 0) curRoot = sPack & 16383;
        else if (ph == 1) {
            // binary-lifting walk: jump ceil(diam/2) parent-hops from v.
            // J tables overlay A (scanS dead until round 2 rebuilds it).
            int diam = sPack >> 14, v = sPack & 16383;
            int steps = diam - (diam >> 1);
            unsigned short* J  = (unsigned short*)A;
            unsigned short* J2 = (unsigned short*)(A + 18432);
            for (int x = tid; x < Nn; x += 1024)
                J[x] = (unsigned short)((x == curRoot) ? x : (x + dir_delta(parC[x])));
            if (tid == 0) sCenter = v;
            __syncthreads();
            for (int k = 0; (steps >> k) != 0; k++) {
                if (tid == 0 && ((steps >> k) & 1)) sCenter = J[sCenter];
                if ((steps >> (k + 1)) != 0) {
                    __syncthreads();
                    for (int x = tid; x < Nn; x += 1024) J2[x] = J[J[x]];
                    __syncthreads();
                    unsigned short* t = J; J = J2; J2 = t;
                }
            }
            __syncthreads();
            curRoot = sCenter;
            rootC = curRoot;
        }
        __syncthreads();   // protect sPack/sR reset next round
    }
    const int D = (sPack >> 14) + 1;

    // ---- counting sort by depth (A free: scanS dead) ----
    unsigned short* posOf = (unsigned short*)A;        // [Nn]
    int* hist   = (int*)(A + 18432);                   // [2048]
    int* levOff = (int*)(A + 26624);                   // [2048]
    for (int k = tid; k < 2048; k += 1024) hist[k] = 0;
    __syncthreads();
    for (int v = tid; v < Nn; v += 1024) atomicAdd(&hist[depthB[v]], 1);
    __syncthreads();
    {
        int h0 = hist[2 * tid], h1 = hist[2 * tid + 1];
        int partial = h0 + h1;
        int incl = scan1024s(partial, tid, wsum);
        int eb = incl - partial;
        levOff[2 * tid] = eb;
        levOff[2 * tid + 1] = eb + h0;
    }
    __syncthreads();
    for (int d = tid; d <= D && d < 2048; d += 1024) levG[d] = levOff[d];
    for (int k = tid; k < 2048; k += 1024) hist[k] = 0;
    __syncthreads();
    for (int v = tid; v < Nn; v += 1024) {
        int dep = depthB[v];
        int pos = levOff[dep] + atomicAdd(&hist[dep], 1);
        posOf[v] = (unsigned short)pos;
        ordG[pos] = v;
    }
    __syncthreads();

    // ---- packed pair {w_bits, ppos} (parC rooted at center), batched ----
    {
        unsigned char rdA[9]; unsigned short posA[9];
        #pragma unroll
        for (int t = 0; t < 9; t++) {
            int v = tid + t * 1024;
            rdA[t] = parC[v]; posA[t] = posOf[v];
        }
        double ewv[9]; unsigned short ppv[9];
        #pragma unroll
        for (int t = 0; t < 9; t++) {
            int v = tid + t * 1024;
            int rd = rdA[t] & 3;
            bool ir = (v == rootC);
            int p  = ir ? v : v + dir_delta(rd);
            int ei = ir ? 0 : edge_of(v, rd);
            ppv[t] = posOf[p];
            ewv[t] = ew[ei];
        }
        #pragma unroll
        for (int t = 0; t < 9; t++) {
            int v = tid + t * 1024;
            int pos = posA[t];
            if (v == rootC) {
                pairG[pos] = make_uint2(0u, 0u);   // w=0.0f
            } else {
                float w = expf(-(float)ewv[t] * inv_sigma);
                pairG[pos] = make_uint2(__float_as_uint(w), (unsigned)ppv[t]);
            }
        }
    }
    if (tid == 0) dG[tb] = D;
}

// Single-wave two-pass tree DP — R20: per-level fences REMOVED.
// Correctness holds without them: all Al[] accesses use runtime indices so
// they may-alias -> compiler preserves their program order; the single-wave
// in-order DS queue preserves it in hardware. pairS/levS are distinct
// no-alias objects, so the scheduler may pipeline them across levels —
// taking them off the serial chain.
__global__ void __launch_bounds__(64)
k_dp(char* __restrict__ ws, int tree, int inMode) {
    const int bc = blockIdx.x;
    const int b = bc / NCh, c = bc % NCh;
    const int tb = tree * Bn + b;
    const int lane = threadIdx.x;
    const int*   ordG  = (const int*)(ws + OFF_ORD)  + (size_t)tb * Nn;
    const uint2* pairG = (const uint2*)(ws + OFF_PAIR) + (size_t)tb * Nn;
    const int*   levG  = (const int*)(ws + OFF_LEV)  + (size_t)tb * MAXD;
    const int D = ((const int*)(ws + OFF_D))[tb];
    const float* src = (inMode == 0)
        ? (const float*)(ws + OFF_PROB) + ((size_t)b * Cc + c) * Nn
        : (const float*)(ws + OFF_S1)   + ((size_t)b * NCh + c) * Nn;
    const float* srcN = (const float*)(ws + OFF_S1) + ((size_t)b * NCh + Cc) * Nn;
    float* dst = (float*)(ws + (tree ? OFF_S2 : OFF_S1)) + ((size_t)b * NCh + c) * Nn;

    __shared__ alignas(16) float Al[Nn];
    __shared__ alignas(16) uint2 pairS[Nn];
    __shared__ unsigned short levS[MAXD];

    // stage packed topology in LDS (vectorized, 2 pairs per uint4)
    {
        const uint4* pg4 = (const uint4*)pairG;
        uint4* ps4 = (uint4*)pairS;
        for (int k = lane; k < Nn / 2; k += 64) ps4[k] = pg4[k];
    }
    for (int d = lane; d <= D && d < MAXD; d += 64) levS[d] = (unsigned short)levG[d];
    if (c == Cc)            { for (int i = lane; i < Nn; i += 64) Al[i] = 1.0f; }
    else if (inMode == 0)   { for (int i = lane; i < Nn; i += 64) Al[i] = src[ordG[i]]; }
    else                    { for (int i = lane; i < Nn; i += 64) { int nd = ordG[i]; Al[i] = src[nd] / srcN[nd]; } }
    __builtin_amdgcn_wave_barrier();
    asm volatile("" ::: "memory");

    // up: children before parents (ds_add_f32, no return). No per-level
    // fence: Al ops stay ordered by may-alias; pairS/levS pipeline freely.
    if (D > 1) {
        for (int d = D - 1; d >= 1; d--) {
            int sd = levS[d], sd1 = levS[d + 1];
            for (int i = sd + lane; i < sd1; i += 64) {
                uint2 pk = pairS[i];
                atomicAdd(&Al[pk.y], __uint_as_float(pk.x) * Al[i]);
            }
        }
    }
    // down: parents before children. Same ordering argument.
    if (D > 1) {
        for (int d = 1; d < D; d++) {
            int sd = levS[d], sd1 = levS[d + 1];
            for (int i = sd + lane; i < sd1; i += 64) {
                uint2 pk = pairS[i];
                float w = __uint_as_float(pk.x);
                float a = Al[i];
                Al[i] = a + w * (Al[pk.y] - w * a);
            }
        }
    }
    __builtin_amdgcn_wave_barrier();
    asm volatile("" ::: "memory");
    for (int i = lane; i < Nn; i += 64) dst[ordG[i]] = Al[i];
}

__global__ void k_loss(char* __restrict__ ws, const float* __restrict__ roi) {
    const int tid = threadIdx.x;
    int idx = blockIdx.x * 256 + tid;
    const float* prob = (const float*)(ws + OFF_PROB);
    const float* S2   = (const float*)(ws + OFF_S2);
    double* acc = (double*)(ws + OFF_ACC);
    double ls = 0.0, cnt = 0.0;
    if (idx < Bn * Cc * Nn) {
        int b = idx / (Cc * Nn);
        int rem = idx - b * (Cc * Nn);
        int c = rem / Nn, n = rem - c * Nn;
        int h = n / Ww, w2 = n - h * Ww;
        float r = roi[(size_t)b * (2 * Hh) * (2 * Ww) + (size_t)(2 * h) * (2 * Ww) + 2 * w2];
        float as = S2[((size_t)b * NCh + c) * Nn + n] / S2[((size_t)b * NCh + Cc) * Nn + n];
        float pp = prob[((size_t)b * Cc + c) * Nn + n];
        ls = (double)(r * fabsf(pp - as));
        if (c == 0) cnt = (double)r;
    }
    __shared__ double sl[256], sc2[256];
    sl[tid] = ls; sc2[tid] = cnt;
    __syncthreads();
    for (int s = 128; s > 0; s >>= 1) {
        if (tid < s) { sl[tid] += sl[tid + s]; sc2[tid] += sc2[tid + s]; }
        __syncthreads();
    }
    if (tid == 0) { atomicAdd(acc, sl[0]); atomicAdd(acc + 1, sc2[0]); }
}

__global__ void k_final(const double* __restrict__ acc, float* __restrict__ out) {
    if (blockIdx.x == 0 && threadIdx.x == 0)
        out[0] = (acc[1] > 0.0) ? (float)(acc[0] / acc[1]) : 0.0f;
}

extern "C" void kernel_launch(void* const* d_in, const int* in_sizes, int n_in,
                              void* d_out, int out_size, void* d_ws, size_t ws_size,
                              hipStream_t stream) {
    const float* preds = (const float*)d_in[0];
    const float* lowf  = (const float*)d_in[1];
    const float* highf = (const float*)d_in[2];
    const float* roi   = (const float*)d_in[3];
    char* ws = (char*)d_ws;
    float* out = (float*)d_out;
    double* ewl = (double*)(ws + OFF_EW);
    double* ewh = (double*)(ws + OFF_EW) + (size_t)Bn * Ne;

    k_prep<<<NB_INIT + 2 * NB_EDGE, 256, 0, stream>>>(
        preds, lowf, highf, (float*)(ws + OFF_PROB), (double*)(ws + OFF_ACC),
        ewl, ewh);
    k_mst<<<8, 1024, 0, stream>>>(ws);
    k_topo<<<8, 1024, 0, stream>>>(ws);
    k_dp<<<Bn * NCh, 64, 0, stream>>>(ws, 0, 0);
    k_dp<<<Bn * NCh, 64, 0, stream>>>(ws, 1, 1);
    k_loss<<<(Bn * Cc * Nn + 255) / 256, 256, 0, stream>>>(ws, roi);
    k_final<<<1, 64, 0, stream>>>((const double*)(ws + OFF_ACC), out);
}